// Round 7
// baseline (262.063 us; speedup 1.0000x reference)
//
#include <hip/hip_runtime.h>
#include <hip/hip_bf16.h>
#include <math.h>

typedef unsigned short u16;
typedef unsigned int u32;
typedef __attribute__((ext_vector_type(8))) short bf16x8;   // 8 bf16 = 4 VGPRs
typedef __attribute__((ext_vector_type(4))) float f32x4;
typedef __attribute__((ext_vector_type(16))) float f32x16;

#define MFMA16(a,b,c) __builtin_amdgcn_mfma_f32_16x16x32_bf16(a,b,c,0,0,0)
#define MFMA32(a,b,c) __builtin_amdgcn_mfma_f32_32x32x16_bf16(a,b,c,0,0,0)

__device__ __forceinline__ u16 f2b(float f){
  unsigned u = __float_as_uint(f);
  u += 0x7fffu + ((u >> 16) & 1u);      // RNE
  return (u16)(u >> 16);
}
__device__ __forceinline__ u32 pack2(float a, float b){
  return (u32)f2b(a) | ((u32)f2b(b) << 16);
}
// packed f32x2 -> bf16x2 (RNE), single VALU op
__device__ __forceinline__ u32 cvtpk(float lo, float hi){
  u32 r; asm("v_cvt_pk_bf16_f32 %0, %1, %2" : "=v"(r) : "v"(lo), "v"(hi)); return r;
}

// async global->LDS, 16B per lane; LDS dest = wave-uniform base + lane*16
__device__ __forceinline__ void gll16(const void* g, void* l){
  __builtin_amdgcn_global_load_lds(
      (__attribute__((address_space(1))) void*)(const_cast<void*>(g)),
      (__attribute__((address_space(3))) void*)l, 16, 0, 0);
}

// ---------------- merged conversions ----------------
// blocks [0,4096): x -> bf16.  blocks [4096,5120): transpose-convert weights.
__global__ __launch_bounds__(256) void conv_k(
    const float* __restrict__ x,  const float* __restrict__ wq,
    const float* __restrict__ wk, const float* __restrict__ wv,
    const float* __restrict__ wo, u16* __restrict__ xb,
    u16* __restrict__ wqkvT, u16* __restrict__ woT)
{
  const int bid = blockIdx.x;
  if (bid < 4096){
    size_t i = ((size_t)bid*256 + threadIdx.x)*8;
    float4 a = *(const float4*)(x+i);
    float4 b = *(const float4*)(x+i+4);
    uint4 u;
    u.x = pack2(a.x, a.y);
    u.y = pack2(a.z, a.w);
    u.z = pack2(b.x, b.y);
    u.w = pack2(b.z, b.w);
    *(uint4*)(xb+i) = u;
    return;
  }
  const int id = bid - 4096;            // 0..1023
  const int z = id >> 8, rem = id & 255, i = rem >> 4, j = rem & 15;
  const float* src = (z==0)?wq:(z==1)?wk:(z==2)?wv:wo;
  u16* dst = (z<3) ? (wqkvT + (size_t)z*1024*1024) : woT;
  __shared__ u16 tile[64][72];
  const int t = threadIdx.x;
  const int cr = t >> 4, cc4 = (t & 15) * 4;
#pragma unroll
  for (int rr = 0; rr < 4; rr++){
    int r = rr*16 + cr;
    float4 v = *(const float4*)(src + (size_t)(i*64 + r)*1024 + j*64 + cc4);
    tile[cc4+0][r] = f2b(v.x);
    tile[cc4+1][r] = f2b(v.y);
    tile[cc4+2][r] = f2b(v.z);
    tile[cc4+3][r] = f2b(v.w);
  }
  __syncthreads();
  const int ro = t >> 2, co = (t & 3) * 16;
  uint4 a = *(uint4*)&tile[ro][co];
  uint4 b = *(uint4*)&tile[ro][co+8];
  u16* p = dst + (size_t)(j*64 + ro)*1024 + i*64 + co;
  *(uint4*)p = a;
  *(uint4*)(p+8) = b;
}

// ---------------- 128x128 bf16 GEMM mainloop, BK=64, C = A[M][K] * B[N][K]^T ------
// LDS row = 64 u16 (8 chunks of 8); chunk slot = ch ^ (row&7). 16 iters at K=1024.
__device__ __forceinline__ void gemm128_bt(
    const u16* __restrict__ A, const u16* __restrict__ B, int K,
    int rowBase, int colBase, f32x4 acc[4][4])
{
  __shared__ __align__(16) u16 lA[128*64];
  __shared__ __align__(16) u16 lB[128*64];
  const int tid = threadIdx.x, lane = tid & 63, wave = tid >> 6;
  const int wr = wave >> 1, wc = wave & 1;
  const int qd = lane >> 4, c = lane & 15;

  int aOff[4], bOff[4];                 // kb=1 offset = kb0 ^ 32
#pragma unroll
  for (int mi=0;mi<4;mi++){ int row = wr*64 + mi*16 + c; aOff[mi] = row*64 + ((qd ^ (row&7))*8); }
#pragma unroll
  for (int ni=0;ni<4;ni++){ int row = wc*64 + ni*16 + c; bOff[ni] = row*64 + ((qd ^ (row&7))*8); }

  const u16* gA[4]; const u16* gB[4]; int seg[4];
#pragma unroll
  for (int cc=0;cc<4;cc++){
    int s = wave*4 + cc;
    int row = s*8 + (lane>>3);
    int gch = (lane&7) ^ (row&7);
    gA[cc] = A + (size_t)(rowBase+row)*K + gch*8;
    gB[cc] = B + (size_t)(colBase+row)*K + gch*8;
    seg[cc] = s*512;
  }
#pragma unroll
  for (int mi=0;mi<4;mi++)
#pragma unroll
    for (int ni=0;ni<4;ni++)
#pragma unroll
      for (int e=0;e<4;e++) acc[mi][ni][e]=0.f;

  for (int k0=0; k0<K; k0+=64){
#pragma unroll
    for (int cc=0;cc<4;cc++){
      gll16(gA[cc] + k0, &lA[seg[cc]]);
      gll16(gB[cc] + k0, &lB[seg[cc]]);
    }
    __syncthreads();
#pragma unroll
    for (int kb=0; kb<2; kb++){
      const int x = kb*32;
      bf16x8 af[4], bb[4];
#pragma unroll
      for (int mi=0;mi<4;mi++) af[mi] = *(const bf16x8*)(lA + (aOff[mi]^x));
#pragma unroll
      for (int ni=0;ni<4;ni++) bb[ni] = *(const bf16x8*)(lB + (bOff[ni]^x));
#pragma unroll
      for (int ni=0;ni<4;ni++)
#pragma unroll
        for (int mi=0;mi<4;mi++)
          acc[mi][ni] = MFMA16(af[mi], bb[ni], acc[mi][ni]);
    }
    __syncthreads();
  }
}

// ---------------- QKV GEMM + RoPE epilogue ----------------
// q pre-scaled by QSC = log2(e)/128 so attention uses exp2 directly.
// RoPE'd dims stored INTERLEAVED: d' = 2j   -> rotated-even of pair j,
//                                 d' = 2j+1 -> rotated-odd  of pair j  (j in [0,32)).
// d' in [64,128) = pass-through. Same permutation for q and k => dot products exact.
// V stored as [bh][t/4][d][4]  ("v4" layout): thread's 4 consecutive-t accs land
// contiguous; lanes adjacent in d -> 4x128B segments per store.
#define QSC (1.44269504088896f/128.0f)
__global__ __launch_bounds__(256) void gemm_qkv_k(
    const u16* __restrict__ xb, const u16* __restrict__ wqkvT,
    u16* __restrict__ q, u16* __restrict__ k, u16* __restrict__ vT)
{
  f32x4 acc[4][4];
  const int rowBase = blockIdx.x*128, colBase = blockIdx.y*128;
  gemm128_bt(xb, wqkvT, 1024, rowBase, colBase, acc);
  const int tid = threadIdx.x, lane = tid & 63, wave = tid >> 6;
  const int wr = wave >> 1, wc = wave & 1;
  const int qd = lane >> 4, c = lane & 15;
  const int nb = blockIdx.y;
  const int proj = nb >> 3, h = nb & 7;

  if (proj < 2){
    u16* dst = (proj==0) ? q : k;
    const float os = (proj==0) ? QSC : 1.0f;
    if (wc == 0){
      // pairs j=c (tiles 0,2) and j=c+16 (tiles 1,3)
      float ang0 = __powf(10000.0f, -(float)c      * (1.0f/32.0f));
      float ang1 = __powf(10000.0f, -(float)(c+16) * (1.0f/32.0f));
#pragma unroll
      for (int mi=0;mi<4;mi++){
#pragma unroll
        for (int r=0;r<4;r++){
          int row = rowBase + wr*64 + mi*16 + qd*4 + r;
          int b = row >> 11, t = row & 2047;
          u32* dst32 = (u32*)(dst + (((long)(b*8+h))*2048 + t)*128);
          float s0,c0,s1,c1;
          __sincosf((float)t*ang0, &s0, &c0);
          __sincosf((float)t*ang1, &s1, &c1);
          { float e = acc[mi][0][r], od = acc[mi][2][r];
            dst32[c]      = pack2((e*c0 - od*s0)*os, (e*s0 + od*c0)*os); }
          { float e = acc[mi][1][r], od = acc[mi][3][r];
            dst32[16 + c] = pack2((e*c1 - od*s1)*os, (e*s1 + od*c1)*os); }
        }
      }
    } else {
      // pass-through half d in [64,128)
#pragma unroll
      for (int mi=0;mi<4;mi++){
#pragma unroll
        for (int r=0;r<4;r++){
          int row = rowBase + wr*64 + mi*16 + qd*4 + r;
          int b = row >> 11, t = row & 2047;
          long base = (((long)(b*8+h))*2048 + t)*128 + 64;
#pragma unroll
          for (int ni=0;ni<4;ni++)
            dst[base + ni*16 + c] = f2b(acc[mi][ni][r]*os);
        }
      }
    }
  } else {
    // v: [bh][t/4][d][4]; acc[mi][ni][0..3] = 4 consecutive t at one d.
#pragma unroll
    for (int mi=0;mi<4;mi++){
      int row0 = rowBase + wr*64 + mi*16 + qd*4;
      int b = row0 >> 11, t = row0 & 2047;
      long base = ((long)(b*8+h)*512 + (t>>2)) * 512;   // *(128 d * 4)
#pragma unroll
      for (int ni=0;ni<4;ni++){
        int d = wc*64 + ni*16 + c;
        *(uint2*)(vT + base + d*4) = make_uint2(pack2(acc[mi][ni][0], acc[mi][ni][1]),
                                                pack2(acc[mi][ni][2], acc[mi][ni][3]));
      }
    }
  }
}

// ---------------- flash attention ----------------
// 256 blocks x 512 thr, heavy+light sub pairing, KVBLK=128 (r6 macro-structure).
// NEW (r7): the two 32-key groups of each iteration are SOFTWARE-PIPELINED in a
// branchless hot loop (kt < qt: no masking possible since key < qt*128 <= qw):
//   - QK chains of group0/group1 interleaved (dependent MFMA spacing 2x)
//   - softmax0 overlaps QK1 completion; softmax1 overlaps PV0 (MFMA only blocks
//     consumers, m114 MFMA||VALU co-issue)
// Tail iteration kt==qt keeps the guarded diag-masked path.
// T12: P in-register via cvt_pk_bf16 + permlane32_swap (HW-verified r3).
// launch_bounds(512,2): do NOT force 4 waves/EU (r3: spill cliff).
// LDS 128KB: K [2][128 key][128 d] swiz ^(row&15); V [2][32 t4][128 d][4] linear.
__global__ __launch_bounds__(512, 2) void attn_k(
    const u16* __restrict__ q, const u16* __restrict__ k,
    const u16* __restrict__ vT, u16* __restrict__ o)
{
  __shared__ __align__(16) u16 smem[65536];        // 128 KB
  u16* lK = smem;                                  // [2][128 key][128 d], swiz ^(row&15)
  u16* lV = smem + 32768;                          // [2][32 t4][128 d][4], linear
  float* scrO = (float*)smem;                      // epilogue [16][32][32] f32 = 64KB
  float* scrL = (float*)(smem + 32768);            // epilogue [2][128] (into lV region)

  const int tid = threadIdx.x, lane = tid & 63, wave = tid >> 6;
  const int h2 = lane >> 5, ln = lane & 31;
  const int qs = wave >> 1, kh = wave & 1;
  const int bh = blockIdx.x, p = blockIdx.y;

  auto loadKV = [&](int kt, int buf){
    const u16* kSrc = k + ((long)bh*2048 + kt*128)*128;
#pragma unroll
    for (int cc=0; cc<4; cc++){
      int s = wave*4+cc;              // 0..31 segs of 1KB
      int row = s*4 + (lane>>4);      // 0..127
      int gch = (lane&15) ^ (row&15);
      gll16(kSrc + row*128 + gch*8, lK + buf*16384 + s*512);
    }
    const u16* vSrc = vT + (long)bh*262144 + (long)kt*16384;  // 32KB tile, contiguous
#pragma unroll
    for (int cc=0; cc<4; cc++){
      int s = wave*4+cc;
      gll16(vSrc + s*512 + lane*8, lV + buf*16384 + s*512);
    }
  };

  for (int sub=0; sub<2; sub++){
    const int qt = sub ? (15 - p) : p;
    const int q0 = qt*128;
    const int qw = q0 + qs*32;          // wave's q-strip base

    bf16x8 aQ[8];
    {
      const long qrow = (long)bh*2048 + qw + ln;
#pragma unroll
      for (int ch=0; ch<8; ch++)
        aQ[ch] = *(const bf16x8*)(q + qrow*128 + ch*16 + h2*8);
    }
    f32x16 accO[4];
#pragma unroll
    for (int dt=0; dt<4; dt++)
#pragma unroll
      for (int r=0;r<16;r++) accO[dt][r] = 0.f;
    float lsum = 0.f;

    __syncthreads();                    // prior sub's LDS users done
    loadKV(0, 0);
    int cur = 0;

    const int krow0 = kh*64 + ln;       // group0 key row in tile
    const int ksw   = (krow0&15)*8;     // swizzle slot base (same for krow0+32)

    // ---------------- HOT LOOP: kt < qt, branchless, 2-group pipeline ----------
    for (int kt=0; kt<qt; kt++){
      __syncthreads();                  // buf[cur] ready; buf[cur^1] readers done
      loadKV(kt+1, cur^1);

      const u16* lkb = lK + cur*16384;
      f32x16 s0, s1;
#pragma unroll
      for (int r=0;r<16;r++){ s0[r]=0.f; s1[r]=0.f; }
#pragma unroll
      for (int ch=0; ch<8; ch++){       // interleaved dependent chains
        int sl = ((ch*2+h2)*8) ^ ksw;
        bf16x8 ak0 = *(const bf16x8*)(lkb +  krow0      *128 + sl);
        bf16x8 ak1 = *(const bf16x8*)(lkb + (krow0 + 32)*128 + sl);
        s0 = MFMA32(ak0, aQ[ch], s0);
        s1 = MFMA32(ak1, aQ[ch], s1);
      }

      // ---- softmax group 0 (overlaps tail of QK1 chain) ----
      float pe[16]; float a0=0.f, a1=0.f;
#pragma unroll
      for (int r=0;r<16;r++){ pe[r]=exp2f(s0[r]); if(r&1) a1+=pe[r]; else a0+=pe[r]; }
      lsum += a0 + a1;
      u32 w0=cvtpk(pe[0],pe[1]),   w1=cvtpk(pe[2],pe[3]);
      u32 w2=cvtpk(pe[4],pe[5]),   w3=cvtpk(pe[6],pe[7]);
      u32 w4=cvtpk(pe[8],pe[9]),   w5=cvtpk(pe[10],pe[11]);
      u32 w6=cvtpk(pe[12],pe[13]), w7=cvtpk(pe[14],pe[15]);
      asm volatile("v_permlane32_swap_b32 %0, %1" : "+v"(w0), "+v"(w2));
      asm volatile("v_permlane32_swap_b32 %0, %1" : "+v"(w1), "+v"(w3));
      asm volatile("v_permlane32_swap_b32 %0, %1" : "+v"(w4), "+v"(w6));
      asm volatile("v_permlane32_swap_b32 %0, %1" : "+v"(w5), "+v"(w7));
      union { bf16x8 v; u32 u[4]; } g0a, g0b;
      g0a.u[0]=w0; g0a.u[1]=w1; g0a.u[2]=w2; g0a.u[3]=w3;   // keys +0..15
      g0b.u[0]=w4; g0b.u[1]=w5; g0b.u[2]=w6; g0b.u[3]=w7;   // keys +16..31

      // ---- PV group 0 (MFMAs issue; wave proceeds to softmax1 under them) ----
      const u16* lvb = lV + cur*16384;
#pragma unroll
      for (int s16=0; s16<2; s16++){
        bf16x8 ap = s16 ? g0b.v : g0a.v;
        const int t4l = kh*16 + s16*4 + h2*2;
#pragma unroll
        for (int dt=0; dt<4; dt++){
          const u16* vp = lvb + (t4l*128 + dt*32 + ln)*4;
          union { bf16x8 v; uint2 u[2]; } bb;
          bb.u[0] = *(const uint2*)(vp);
          bb.u[1] = *(const uint2*)(vp + 512);
          accO[dt] = MFMA32(ap, bb.v, accO[dt]);
        }
      }

      // ---- softmax group 1 (overlaps PV0 MFMAs) ----
      float b0=0.f, b1=0.f;
#pragma unroll
      for (int r=0;r<16;r++){ pe[r]=exp2f(s1[r]); if(r&1) b1+=pe[r]; else b0+=pe[r]; }
      lsum += b0 + b1;
      w0=cvtpk(pe[0],pe[1]);   w1=cvtpk(pe[2],pe[3]);
      w2=cvtpk(pe[4],pe[5]);   w3=cvtpk(pe[6],pe[7]);
      w4=cvtpk(pe[8],pe[9]);   w5=cvtpk(pe[10],pe[11]);
      w6=cvtpk(pe[12],pe[13]); w7=cvtpk(pe[14],pe[15]);
      asm volatile("v_permlane32_swap_b32 %0, %1" : "+v"(w0), "+v"(w2));
      asm volatile("v_permlane32_swap_b32 %0, %1" : "+v"(w1), "+v"(w3));
      asm volatile("v_permlane32_swap_b32 %0, %1" : "+v"(w4), "+v"(w6));
      asm volatile("v_permlane32_swap_b32 %0, %1" : "+v"(w5), "+v"(w7));
      union { bf16x8 v; u32 u[4]; } g1a, g1b;
      g1a.u[0]=w0; g1a.u[1]=w1; g1a.u[2]=w2; g1a.u[3]=w3;
      g1b.u[0]=w4; g1b.u[1]=w5; g1b.u[2]=w6; g1b.u[3]=w7;

      // ---- PV group 1 ----
#pragma unroll
      for (int s16=0; s16<2; s16++){
        bf16x8 ap = s16 ? g1b.v : g1a.v;
        const int t4l = kh*16 + (2+s16)*4 + h2*2;
#pragma unroll
        for (int dt=0; dt<4; dt++){
          const u16* vp = lvb + (t4l*128 + dt*32 + ln)*4;
          union { bf16x8 v; uint2 u[2]; } bb;
          bb.u[0] = *(const uint2*)(vp);
          bb.u[1] = *(const uint2*)(vp + 512);
          accO[dt] = MFMA32(ap, bb.v, accO[dt]);
        }
      }
      cur ^= 1;
    }

    // ---------------- TAIL: kt == qt, guarded + diag-masked ----------------
    {
      const int kt = qt;
      __syncthreads();
#pragma unroll
      for (int g2=0; g2<2; g2++){
        const int key0 = kt*128 + kh*64 + g2*32;
        if (key0 <= qw + 31){
          f32x16 accS;
#pragma unroll
          for (int r=0;r<16;r++) accS[r] = 0.f;
          const int krow = kh*64 + g2*32 + ln;
#pragma unroll
          for (int ch=0; ch<8; ch++){
            bf16x8 ak = *(const bf16x8*)(lK + cur*16384 + krow*128 + (((ch*2+h2) ^ (krow&15))*8));
            accS = MFMA32(ak, aQ[ch], accS);
          }
          const bool diag = (key0 + 31 > qw);
          float pe[16];
          float ls0 = 0.f, ls1 = 0.f;
#pragma unroll
          for (int r=0;r<16;r++){
            float s = accS[r];
            if (diag){
              int keyg = key0 + (r&3) + 8*(r>>2) + 4*h2;
              if (keyg > qw + ln) s = -INFINITY;   // exp2(-inf) = 0
            }
            pe[r] = exp2f(s);
            if (r & 1) ls1 += pe[r]; else ls0 += pe[r];
          }
          lsum += ls0 + ls1;

          u32 w0 = cvtpk(pe[0],  pe[1]),  w1 = cvtpk(pe[2],  pe[3]);
          u32 w2 = cvtpk(pe[4],  pe[5]),  w3 = cvtpk(pe[6],  pe[7]);
          u32 w4 = cvtpk(pe[8],  pe[9]),  w5 = cvtpk(pe[10], pe[11]);
          u32 w6 = cvtpk(pe[12], pe[13]), w7 = cvtpk(pe[14], pe[15]);
          asm volatile("v_permlane32_swap_b32 %0, %1" : "+v"(w0), "+v"(w2));
          asm volatile("v_permlane32_swap_b32 %0, %1" : "+v"(w1), "+v"(w3));
          asm volatile("v_permlane32_swap_b32 %0, %1" : "+v"(w4), "+v"(w6));
          asm volatile("v_permlane32_swap_b32 %0, %1" : "+v"(w5), "+v"(w7));
          union { bf16x8 v; u32 u[4]; } ap0, ap1;
          ap0.u[0]=w0; ap0.u[1]=w1; ap0.u[2]=w2; ap0.u[3]=w3;
          ap1.u[0]=w4; ap1.u[1]=w5; ap1.u[2]=w6; ap1.u[3]=w7;

#pragma unroll
          for (int s16=0; s16<2; s16++){
            bf16x8 ap = s16 ? ap1.v : ap0.v;
            const int kk = g2*2 + s16;
            const int t4l = kh*16 + kk*4 + h2*2;
#pragma unroll
            for (int dt=0; dt<4; dt++){
              int d = dt*32 + ln;
              const u16* vp = lV + cur*16384 + (t4l*128 + d)*4;
              union { bf16x8 v; uint2 u[2]; } bb;
              bb.u[0] = *(const uint2*)(vp);
              bb.u[1] = *(const uint2*)(vp + 512);
              accO[dt] = MFMA32(ap, bb.v, accO[dt]);
            }
          }
        }
      }
    }

    // ---- epilogue: combine kh halves, normalize, store ----
    lsum += __shfl_xor(lsum, 32);       // fold h2 halves
    __syncthreads();                    // main-loop LDS reads done before alias reuse
    if (kh == 1){
#pragma unroll
      for (int dt=0; dt<4; dt++)
#pragma unroll
        for (int r=0;r<16;r++){
          int row = (r&3) + 8*(r>>2) + 4*h2;
          scrO[((qs*4+dt)*32 + row)*32 + ln] = accO[dt][r];
        }
      if (h2 == 0) scrL[128 + qs*32 + ln] = lsum;
    } else {
      if (h2 == 0) scrL[qs*32 + ln] = lsum;
    }
    __syncthreads();
    if (kh == 0){
      float linv[16];
#pragma unroll
      for (int r=0;r<16;r++){
        int row = (r&3) + 8*(r>>2) + 4*h2;
        linv[r] = 1.0f / (scrL[qs*32 + row] + scrL[128 + qs*32 + row]);
      }
      const int b = bh >> 3, h = bh & 7;
#pragma unroll
      for (int dt=0; dt<4; dt++){
#pragma unroll
        for (int r=0;r<16;r++){
          int row = (r&3) + 8*(r>>2) + 4*h2;
          float val = accO[dt][r] + scrO[((qs*4+dt)*32 + row)*32 + ln];
          int t = q0 + qs*32 + row;
          o[((long)(b*2048 + t))*1024 + h*128 + dt*32 + ln] = f2b(val * linv[r]);
        }
      }
    }
  }
}

// ---------------- output projection ----------------
__global__ __launch_bounds__(256) void gemm_out_k(
    const u16* __restrict__ oa, const u16* __restrict__ woT, float* __restrict__ out)
{
  f32x4 acc[4][4];
  const int rowBase = blockIdx.x*128, colBase = blockIdx.y*128;
  gemm128_bt(oa, woT, 1024, rowBase, colBase, acc);
  const int lane = threadIdx.x & 63, wave = threadIdx.x >> 6;
  const int wr = wave >> 1, wc = wave & 1;
  const int qd = lane >> 4, c = lane & 15;
#pragma unroll
  for (int mi=0;mi<4;mi++){
#pragma unroll
    for (int ni=0;ni<4;ni++){
      int row = rowBase + wr*64 + mi*16 + qd*4;
      int col = colBase + wc*64 + ni*16 + c;
#pragma unroll
      for (int r=0;r<4;r++)
        out[(size_t)(row+r)*1024 + col] = acc[mi][ni][r];
    }
  }
}

extern "C" void kernel_launch(void* const* d_in, const int* in_sizes, int n_in,
                              void* d_out, int out_size, void* d_ws, size_t ws_size,
                              hipStream_t stream) {
  const float* x  = (const float*)d_in[0];
  const float* wq = (const float*)d_in[1];
  const float* wk = (const float*)d_in[2];
  const float* wv = (const float*)d_in[3];
  const float* wo = (const float*)d_in[4];
  float* out = (float*)d_out;

  char* ws = (char*)d_ws;
  u16* xb    = (u16*)(ws);
  u16* wqkvT = (u16*)(ws + (16u<<20));
  u16* woT   = (u16*)(ws + (22u<<20));
  u16* qb    = (u16*)(ws + (24u<<20));
  u16* kb    = (u16*)(ws + (40u<<20));
  u16* vT    = (u16*)(ws + (56u<<20));
  u16* ob    = xb;   // reuse xb after gemm_qkv

  conv_k    <<<dim3(5120), dim3(256), 0, stream>>>(x, wq, wk, wv, wo, xb, wqkvT, woT);
  gemm_qkv_k<<<dim3(64,24), dim3(256), 0, stream>>>(xb, wqkvT, qb, kb, vT);
  attn_k    <<<dim3(32,8), dim3(512), 0, stream>>>(qb, kb, vT, ob);
  gemm_out_k<<<dim3(64,8),  dim3(256), 0, stream>>>(ob, woT, out);
}

// Round 8
// 260.792 us; speedup vs baseline: 1.0049x; 1.0049x over previous
//
#include <hip/hip_runtime.h>
#include <hip/hip_bf16.h>
#include <math.h>

typedef unsigned short u16;
typedef unsigned int u32;
typedef __attribute__((ext_vector_type(8))) short bf16x8;   // 8 bf16 = 4 VGPRs
typedef __attribute__((ext_vector_type(4))) float f32x4;
typedef __attribute__((ext_vector_type(16))) float f32x16;

#define MFMA16(a,b,c) __builtin_amdgcn_mfma_f32_16x16x32_bf16(a,b,c,0,0,0)
#define MFMA32(a,b,c) __builtin_amdgcn_mfma_f32_32x32x16_bf16(a,b,c,0,0,0)

__device__ __forceinline__ u16 f2b(float f){
  unsigned u = __float_as_uint(f);
  u += 0x7fffu + ((u >> 16) & 1u);      // RNE
  return (u16)(u >> 16);
}
__device__ __forceinline__ u32 pack2(float a, float b){
  return (u32)f2b(a) | ((u32)f2b(b) << 16);
}
// packed f32x2 -> bf16x2 (RNE), single VALU op
__device__ __forceinline__ u32 cvtpk(float lo, float hi){
  u32 r; asm("v_cvt_pk_bf16_f32 %0, %1, %2" : "=v"(r) : "v"(lo), "v"(hi)); return r;
}

// async global->LDS, 16B per lane; LDS dest = wave-uniform base + lane*16
__device__ __forceinline__ void gll16(const void* g, void* l){
  __builtin_amdgcn_global_load_lds(
      (__attribute__((address_space(1))) void*)(const_cast<void*>(g)),
      (__attribute__((address_space(3))) void*)l, 16, 0, 0);
}

// ---------------- merged conversions ----------------
// blocks [0,4096): x -> bf16.  blocks [4096,5120): transpose-convert weights.
__global__ __launch_bounds__(256) void conv_k(
    const float* __restrict__ x,  const float* __restrict__ wq,
    const float* __restrict__ wk, const float* __restrict__ wv,
    const float* __restrict__ wo, u16* __restrict__ xb,
    u16* __restrict__ wqkvT, u16* __restrict__ woT)
{
  const int bid = blockIdx.x;
  if (bid < 4096){
    size_t i = ((size_t)bid*256 + threadIdx.x)*8;
    float4 a = *(const float4*)(x+i);
    float4 b = *(const float4*)(x+i+4);
    uint4 u;
    u.x = pack2(a.x, a.y);
    u.y = pack2(a.z, a.w);
    u.z = pack2(b.x, b.y);
    u.w = pack2(b.z, b.w);
    *(uint4*)(xb+i) = u;
    return;
  }
  const int id = bid - 4096;            // 0..1023
  const int z = id >> 8, rem = id & 255, i = rem >> 4, j = rem & 15;
  const float* src = (z==0)?wq:(z==1)?wk:(z==2)?wv:wo;
  u16* dst = (z<3) ? (wqkvT + (size_t)z*1024*1024) : woT;
  __shared__ u16 tile[64][72];
  const int t = threadIdx.x;
  const int cr = t >> 4, cc4 = (t & 15) * 4;
#pragma unroll
  for (int rr = 0; rr < 4; rr++){
    int r = rr*16 + cr;
    float4 v = *(const float4*)(src + (size_t)(i*64 + r)*1024 + j*64 + cc4);
    tile[cc4+0][r] = f2b(v.x);
    tile[cc4+1][r] = f2b(v.y);
    tile[cc4+2][r] = f2b(v.z);
    tile[cc4+3][r] = f2b(v.w);
  }
  __syncthreads();
  const int ro = t >> 2, co = (t & 3) * 16;
  uint4 a = *(uint4*)&tile[ro][co];
  uint4 b = *(uint4*)&tile[ro][co+8];
  u16* p = dst + (size_t)(j*64 + ro)*1024 + i*64 + co;
  *(uint4*)p = a;
  *(uint4*)(p+8) = b;
}

// ---------------- 128x128 bf16 GEMM mainloop, BK=64, C = A[M][K] * B[N][K]^T ------
// LDS row = 64 u16 (8 chunks of 8); chunk slot = ch ^ (row&7). 16 iters at K=1024.
__device__ __forceinline__ void gemm128_bt(
    const u16* __restrict__ A, const u16* __restrict__ B, int K,
    int rowBase, int colBase, f32x4 acc[4][4])
{
  __shared__ __align__(16) u16 lA[128*64];
  __shared__ __align__(16) u16 lB[128*64];
  const int tid = threadIdx.x, lane = tid & 63, wave = tid >> 6;
  const int wr = wave >> 1, wc = wave & 1;
  const int qd = lane >> 4, c = lane & 15;

  int aOff[4], bOff[4];                 // kb=1 offset = kb0 ^ 32
#pragma unroll
  for (int mi=0;mi<4;mi++){ int row = wr*64 + mi*16 + c; aOff[mi] = row*64 + ((qd ^ (row&7))*8); }
#pragma unroll
  for (int ni=0;ni<4;ni++){ int row = wc*64 + ni*16 + c; bOff[ni] = row*64 + ((qd ^ (row&7))*8); }

  const u16* gA[4]; const u16* gB[4]; int seg[4];
#pragma unroll
  for (int cc=0;cc<4;cc++){
    int s = wave*4 + cc;
    int row = s*8 + (lane>>3);
    int gch = (lane&7) ^ (row&7);
    gA[cc] = A + (size_t)(rowBase+row)*K + gch*8;
    gB[cc] = B + (size_t)(colBase+row)*K + gch*8;
    seg[cc] = s*512;
  }
#pragma unroll
  for (int mi=0;mi<4;mi++)
#pragma unroll
    for (int ni=0;ni<4;ni++)
#pragma unroll
      for (int e=0;e<4;e++) acc[mi][ni][e]=0.f;

  for (int k0=0; k0<K; k0+=64){
#pragma unroll
    for (int cc=0;cc<4;cc++){
      gll16(gA[cc] + k0, &lA[seg[cc]]);
      gll16(gB[cc] + k0, &lB[seg[cc]]);
    }
    __syncthreads();
#pragma unroll
    for (int kb=0; kb<2; kb++){
      const int x = kb*32;
      bf16x8 af[4], bb[4];
#pragma unroll
      for (int mi=0;mi<4;mi++) af[mi] = *(const bf16x8*)(lA + (aOff[mi]^x));
#pragma unroll
      for (int ni=0;ni<4;ni++) bb[ni] = *(const bf16x8*)(lB + (bOff[ni]^x));
#pragma unroll
      for (int ni=0;ni<4;ni++)
#pragma unroll
        for (int mi=0;mi<4;mi++)
          acc[mi][ni] = MFMA16(af[mi], bb[ni], acc[mi][ni]);
    }
    __syncthreads();
  }
}

// ---------------- QKV GEMM + RoPE epilogue ----------------
// q pre-scaled by QSC = log2(e)/128 so attention uses exp2 directly.
// RoPE'd dims stored INTERLEAVED: d' = 2j   -> rotated-even of pair j,
//                                 d' = 2j+1 -> rotated-odd  of pair j  (j in [0,32)).
// d' in [64,128) = pass-through. Same permutation for q and k => dot products exact.
// V stored as [bh][t/4][d][4]  ("v4" layout): thread's 4 consecutive-t accs land
// contiguous; lanes adjacent in d -> 4x128B segments per store.
#define QSC (1.44269504088896f/128.0f)
__global__ __launch_bounds__(256) void gemm_qkv_k(
    const u16* __restrict__ xb, const u16* __restrict__ wqkvT,
    u16* __restrict__ q, u16* __restrict__ k, u16* __restrict__ vT)
{
  f32x4 acc[4][4];
  const int rowBase = blockIdx.x*128, colBase = blockIdx.y*128;
  gemm128_bt(xb, wqkvT, 1024, rowBase, colBase, acc);
  const int tid = threadIdx.x, lane = tid & 63, wave = tid >> 6;
  const int wr = wave >> 1, wc = wave & 1;
  const int qd = lane >> 4, c = lane & 15;
  const int nb = blockIdx.y;
  const int proj = nb >> 3, h = nb & 7;

  if (proj < 2){
    u16* dst = (proj==0) ? q : k;
    const float os = (proj==0) ? QSC : 1.0f;
    if (wc == 0){
      // pairs j=c (tiles 0,2) and j=c+16 (tiles 1,3)
      float ang0 = __powf(10000.0f, -(float)c      * (1.0f/32.0f));
      float ang1 = __powf(10000.0f, -(float)(c+16) * (1.0f/32.0f));
#pragma unroll
      for (int mi=0;mi<4;mi++){
#pragma unroll
        for (int r=0;r<4;r++){
          int row = rowBase + wr*64 + mi*16 + qd*4 + r;
          int b = row >> 11, t = row & 2047;
          u32* dst32 = (u32*)(dst + (((long)(b*8+h))*2048 + t)*128);
          float s0,c0,s1,c1;
          __sincosf((float)t*ang0, &s0, &c0);
          __sincosf((float)t*ang1, &s1, &c1);
          { float e = acc[mi][0][r], od = acc[mi][2][r];
            dst32[c]      = pack2((e*c0 - od*s0)*os, (e*s0 + od*c0)*os); }
          { float e = acc[mi][1][r], od = acc[mi][3][r];
            dst32[16 + c] = pack2((e*c1 - od*s1)*os, (e*s1 + od*c1)*os); }
        }
      }
    } else {
      // pass-through half d in [64,128)
#pragma unroll
      for (int mi=0;mi<4;mi++){
#pragma unroll
        for (int r=0;r<4;r++){
          int row = rowBase + wr*64 + mi*16 + qd*4 + r;
          int b = row >> 11, t = row & 2047;
          long base = (((long)(b*8+h))*2048 + t)*128 + 64;
#pragma unroll
          for (int ni=0;ni<4;ni++)
            dst[base + ni*16 + c] = f2b(acc[mi][ni][r]*os);
        }
      }
    }
  } else {
    // v: [bh][t/4][d][4]; acc[mi][ni][0..3] = 4 consecutive t at one d.
#pragma unroll
    for (int mi=0;mi<4;mi++){
      int row0 = rowBase + wr*64 + mi*16 + qd*4;
      int b = row0 >> 11, t = row0 & 2047;
      long base = ((long)(b*8+h)*512 + (t>>2)) * 512;   // *(128 d * 4)
#pragma unroll
      for (int ni=0;ni<4;ni++){
        int d = wc*64 + ni*16 + c;
        *(uint2*)(vT + base + d*4) = make_uint2(pack2(acc[mi][ni][0], acc[mi][ni][1]),
                                                pack2(acc[mi][ni][2], acc[mi][ni][3]));
      }
    }
  }
}

// ---------------- flash attention ----------------
// r7 schedule (KVBLK=128, branchless hot loop, 2-group software pipeline) with
// the occupancy contract PINNED: amdgpu_waves_per_eu(2,2). r7 lesson: with
// __launch_bounds__(512,2) (min only) the backend targeted 4 waves/EU and
// spilled ~200 live VGPRs to scratch (WRITE_SIZE 20->45.5MB) while reporting
// 128 VGPRs. 128KB LDS means only 1 block (8 waves = 2/EU) can ever be
// resident, so min=max=2 is truthful and unlocks the 256-VGPR budget.
// T12: P in-register via cvt_pk_bf16 + permlane32_swap (HW-verified r3).
// LDS 128KB: K [2][128 key][128 d] swiz ^(row&15); V [2][32 t4][128 d][4] linear.
__global__
__attribute__((amdgpu_flat_work_group_size(512, 512), amdgpu_waves_per_eu(2, 2)))
void attn_k(
    const u16* __restrict__ q, const u16* __restrict__ k,
    const u16* __restrict__ vT, u16* __restrict__ o)
{
  __shared__ __align__(16) u16 smem[65536];        // 128 KB
  u16* lK = smem;                                  // [2][128 key][128 d], swiz ^(row&15)
  u16* lV = smem + 32768;                          // [2][32 t4][128 d][4], linear
  float* scrO = (float*)smem;                      // epilogue [16][32][32] f32 = 64KB
  float* scrL = (float*)(smem + 32768);            // epilogue [2][128] (into lV region)

  const int tid = threadIdx.x, lane = tid & 63, wave = tid >> 6;
  const int h2 = lane >> 5, ln = lane & 31;
  const int qs = wave >> 1, kh = wave & 1;
  const int bh = blockIdx.x, p = blockIdx.y;

  auto loadKV = [&](int kt, int buf){
    const u16* kSrc = k + ((long)bh*2048 + kt*128)*128;
#pragma unroll
    for (int cc=0; cc<4; cc++){
      int s = wave*4+cc;              // 0..31 segs of 1KB
      int row = s*4 + (lane>>4);      // 0..127
      int gch = (lane&15) ^ (row&15);
      gll16(kSrc + row*128 + gch*8, lK + buf*16384 + s*512);
    }
    const u16* vSrc = vT + (long)bh*262144 + (long)kt*16384;  // 32KB tile, contiguous
#pragma unroll
    for (int cc=0; cc<4; cc++){
      int s = wave*4+cc;
      gll16(vSrc + s*512 + lane*8, lV + buf*16384 + s*512);
    }
  };

  for (int sub=0; sub<2; sub++){
    const int qt = sub ? (15 - p) : p;
    const int q0 = qt*128;
    const int qw = q0 + qs*32;          // wave's q-strip base

    bf16x8 aQ[8];
    {
      const long qrow = (long)bh*2048 + qw + ln;
#pragma unroll
      for (int ch=0; ch<8; ch++)
        aQ[ch] = *(const bf16x8*)(q + qrow*128 + ch*16 + h2*8);
    }
    f32x16 accO[4];
#pragma unroll
    for (int dt=0; dt<4; dt++)
#pragma unroll
      for (int r=0;r<16;r++) accO[dt][r] = 0.f;
    float lsum = 0.f;

    __syncthreads();                    // prior sub's LDS users done
    loadKV(0, 0);
    int cur = 0;

    const int krow0 = kh*64 + ln;       // group0 key row in tile
    const int ksw   = (krow0&15)*8;     // swizzle slot base (same for krow0+32)

    // ---------------- HOT LOOP: kt < qt, branchless, 2-group pipeline ----------
    for (int kt=0; kt<qt; kt++){
      __syncthreads();                  // buf[cur] ready; buf[cur^1] readers done
      loadKV(kt+1, cur^1);

      const u16* lkb = lK + cur*16384;
      f32x16 s0, s1;
#pragma unroll
      for (int r=0;r<16;r++){ s0[r]=0.f; s1[r]=0.f; }
#pragma unroll
      for (int ch=0; ch<8; ch++){       // interleaved dependent chains
        int sl = ((ch*2+h2)*8) ^ ksw;
        bf16x8 ak0 = *(const bf16x8*)(lkb +  krow0      *128 + sl);
        bf16x8 ak1 = *(const bf16x8*)(lkb + (krow0 + 32)*128 + sl);
        s0 = MFMA32(ak0, aQ[ch], s0);
        s1 = MFMA32(ak1, aQ[ch], s1);
      }

      // ---- softmax group 0 (overlaps tail of QK1 chain) ----
      float pe[16]; float a0=0.f, a1=0.f;
#pragma unroll
      for (int r=0;r<16;r++){ pe[r]=exp2f(s0[r]); if(r&1) a1+=pe[r]; else a0+=pe[r]; }
      lsum += a0 + a1;
      u32 w0=cvtpk(pe[0],pe[1]),   w1=cvtpk(pe[2],pe[3]);
      u32 w2=cvtpk(pe[4],pe[5]),   w3=cvtpk(pe[6],pe[7]);
      u32 w4=cvtpk(pe[8],pe[9]),   w5=cvtpk(pe[10],pe[11]);
      u32 w6=cvtpk(pe[12],pe[13]), w7=cvtpk(pe[14],pe[15]);
      asm volatile("v_permlane32_swap_b32 %0, %1" : "+v"(w0), "+v"(w2));
      asm volatile("v_permlane32_swap_b32 %0, %1" : "+v"(w1), "+v"(w3));
      asm volatile("v_permlane32_swap_b32 %0, %1" : "+v"(w4), "+v"(w6));
      asm volatile("v_permlane32_swap_b32 %0, %1" : "+v"(w5), "+v"(w7));
      union { bf16x8 v; u32 u[4]; } g0a, g0b;
      g0a.u[0]=w0; g0a.u[1]=w1; g0a.u[2]=w2; g0a.u[3]=w3;   // keys +0..15
      g0b.u[0]=w4; g0b.u[1]=w5; g0b.u[2]=w6; g0b.u[3]=w7;   // keys +16..31

      // ---- PV group 0 (MFMAs issue; wave proceeds to softmax1 under them) ----
      const u16* lvb = lV + cur*16384;
#pragma unroll
      for (int s16=0; s16<2; s16++){
        bf16x8 ap = s16 ? g0b.v : g0a.v;
        const int t4l = kh*16 + s16*4 + h2*2;
#pragma unroll
        for (int dt=0; dt<4; dt++){
          const u16* vp = lvb + (t4l*128 + dt*32 + ln)*4;
          union { bf16x8 v; uint2 u[2]; } bb;
          bb.u[0] = *(const uint2*)(vp);
          bb.u[1] = *(const uint2*)(vp + 512);
          accO[dt] = MFMA32(ap, bb.v, accO[dt]);
        }
      }

      // ---- softmax group 1 (overlaps PV0 MFMAs) ----
      float b0=0.f, b1=0.f;
#pragma unroll
      for (int r=0;r<16;r++){ pe[r]=exp2f(s1[r]); if(r&1) b1+=pe[r]; else b0+=pe[r]; }
      lsum += b0 + b1;
      w0=cvtpk(pe[0],pe[1]);   w1=cvtpk(pe[2],pe[3]);
      w2=cvtpk(pe[4],pe[5]);   w3=cvtpk(pe[6],pe[7]);
      w4=cvtpk(pe[8],pe[9]);   w5=cvtpk(pe[10],pe[11]);
      w6=cvtpk(pe[12],pe[13]); w7=cvtpk(pe[14],pe[15]);
      asm volatile("v_permlane32_swap_b32 %0, %1" : "+v"(w0), "+v"(w2));
      asm volatile("v_permlane32_swap_b32 %0, %1" : "+v"(w1), "+v"(w3));
      asm volatile("v_permlane32_swap_b32 %0, %1" : "+v"(w4), "+v"(w6));
      asm volatile("v_permlane32_swap_b32 %0, %1" : "+v"(w5), "+v"(w7));
      union { bf16x8 v; u32 u[4]; } g1a, g1b;
      g1a.u[0]=w0; g1a.u[1]=w1; g1a.u[2]=w2; g1a.u[3]=w3;
      g1b.u[0]=w4; g1b.u[1]=w5; g1b.u[2]=w6; g1b.u[3]=w7;

      // ---- PV group 1 ----
#pragma unroll
      for (int s16=0; s16<2; s16++){
        bf16x8 ap = s16 ? g1b.v : g1a.v;
        const int t4l = kh*16 + (2+s16)*4 + h2*2;
#pragma unroll
        for (int dt=0; dt<4; dt++){
          const u16* vp = lvb + (t4l*128 + dt*32 + ln)*4;
          union { bf16x8 v; uint2 u[2]; } bb;
          bb.u[0] = *(const uint2*)(vp);
          bb.u[1] = *(const uint2*)(vp + 512);
          accO[dt] = MFMA32(ap, bb.v, accO[dt]);
        }
      }
      cur ^= 1;
    }

    // ---------------- TAIL: kt == qt, guarded + diag-masked ----------------
    {
      const int kt = qt;
      __syncthreads();
#pragma unroll
      for (int g2=0; g2<2; g2++){
        const int key0 = kt*128 + kh*64 + g2*32;
        if (key0 <= qw + 31){
          f32x16 accS;
#pragma unroll
          for (int r=0;r<16;r++) accS[r] = 0.f;
          const int krow = kh*64 + g2*32 + ln;
#pragma unroll
          for (int ch=0; ch<8; ch++){
            bf16x8 ak = *(const bf16x8*)(lK + cur*16384 + krow*128 + (((ch*2+h2) ^ (krow&15))*8));
            accS = MFMA32(ak, aQ[ch], accS);
          }
          const bool diag = (key0 + 31 > qw);
          float pe[16];
          float ls0 = 0.f, ls1 = 0.f;
#pragma unroll
          for (int r=0;r<16;r++){
            float s = accS[r];
            if (diag){
              int keyg = key0 + (r&3) + 8*(r>>2) + 4*h2;
              if (keyg > qw + ln) s = -INFINITY;   // exp2(-inf) = 0
            }
            pe[r] = exp2f(s);
            if (r & 1) ls1 += pe[r]; else ls0 += pe[r];
          }
          lsum += ls0 + ls1;

          u32 w0 = cvtpk(pe[0],  pe[1]),  w1 = cvtpk(pe[2],  pe[3]);
          u32 w2 = cvtpk(pe[4],  pe[5]),  w3 = cvtpk(pe[6],  pe[7]);
          u32 w4 = cvtpk(pe[8],  pe[9]),  w5 = cvtpk(pe[10], pe[11]);
          u32 w6 = cvtpk(pe[12], pe[13]), w7 = cvtpk(pe[14], pe[15]);
          asm volatile("v_permlane32_swap_b32 %0, %1" : "+v"(w0), "+v"(w2));
          asm volatile("v_permlane32_swap_b32 %0, %1" : "+v"(w1), "+v"(w3));
          asm volatile("v_permlane32_swap_b32 %0, %1" : "+v"(w4), "+v"(w6));
          asm volatile("v_permlane32_swap_b32 %0, %1" : "+v"(w5), "+v"(w7));
          union { bf16x8 v; u32 u[4]; } ap0, ap1;
          ap0.u[0]=w0; ap0.u[1]=w1; ap0.u[2]=w2; ap0.u[3]=w3;
          ap1.u[0]=w4; ap1.u[1]=w5; ap1.u[2]=w6; ap1.u[3]=w7;

#pragma unroll
          for (int s16=0; s16<2; s16++){
            bf16x8 ap = s16 ? ap1.v : ap0.v;
            const int kk = g2*2 + s16;
            const int t4l = kh*16 + kk*4 + h2*2;
#pragma unroll
            for (int dt=0; dt<4; dt++){
              int d = dt*32 + ln;
              const u16* vp = lV + cur*16384 + (t4l*128 + d)*4;
              union { bf16x8 v; uint2 u[2]; } bb;
              bb.u[0] = *(const uint2*)(vp);
              bb.u[1] = *(const uint2*)(vp + 512);
              accO[dt] = MFMA32(ap, bb.v, accO[dt]);
            }
          }
        }
      }
    }

    // ---- epilogue: combine kh halves, normalize, store ----
    lsum += __shfl_xor(lsum, 32);       // fold h2 halves
    __syncthreads();                    // main-loop LDS reads done before alias reuse
    if (kh == 1){
#pragma unroll
      for (int dt=0; dt<4; dt++)
#pragma unroll
        for (int r=0;r<16;r++){
          int row = (r&3) + 8*(r>>2) + 4*h2;
          scrO[((qs*4+dt)*32 + row)*32 + ln] = accO[dt][r];
        }
      if (h2 == 0) scrL[128 + qs*32 + ln] = lsum;
    } else {
      if (h2 == 0) scrL[qs*32 + ln] = lsum;
    }
    __syncthreads();
    if (kh == 0){
      float linv[16];
#pragma unroll
      for (int r=0;r<16;r++){
        int row = (r&3) + 8*(r>>2) + 4*h2;
        linv[r] = 1.0f / (scrL[qs*32 + row] + scrL[128 + qs*32 + row]);
      }
      const int b = bh >> 3, h = bh & 7;
#pragma unroll
      for (int dt=0; dt<4; dt++){
#pragma unroll
        for (int r=0;r<16;r++){
          int row = (r&3) + 8*(r>>2) + 4*h2;
          float val = accO[dt][r] + scrO[((qs*4+dt)*32 + row)*32 + ln];
          int t = q0 + qs*32 + row;
          o[((long)(b*2048 + t))*1024 + h*128 + dt*32 + ln] = f2b(val * linv[r]);
        }
      }
    }
  }
}

// ---------------- output projection ----------------
__global__ __launch_bounds__(256) void gemm_out_k(
    const u16* __restrict__ oa, const u16* __restrict__ woT, float* __restrict__ out)
{
  f32x4 acc[4][4];
  const int rowBase = blockIdx.x*128, colBase = blockIdx.y*128;
  gemm128_bt(oa, woT, 1024, rowBase, colBase, acc);
  const int lane = threadIdx.x & 63, wave = threadIdx.x >> 6;
  const int wr = wave >> 1, wc = wave & 1;
  const int qd = lane >> 4, c = lane & 15;
#pragma unroll
  for (int mi=0;mi<4;mi++){
#pragma unroll
    for (int ni=0;ni<4;ni++){
      int row = rowBase + wr*64 + mi*16 + qd*4;
      int col = colBase + wc*64 + ni*16 + c;
#pragma unroll
      for (int r=0;r<4;r++)
        out[(size_t)(row+r)*1024 + col] = acc[mi][ni][r];
    }
  }
}

extern "C" void kernel_launch(void* const* d_in, const int* in_sizes, int n_in,
                              void* d_out, int out_size, void* d_ws, size_t ws_size,
                              hipStream_t stream) {
  const float* x  = (const float*)d_in[0];
  const float* wq = (const float*)d_in[1];
  const float* wk = (const float*)d_in[2];
  const float* wv = (const float*)d_in[3];
  const float* wo = (const float*)d_in[4];
  float* out = (float*)d_out;

  char* ws = (char*)d_ws;
  u16* xb    = (u16*)(ws);
  u16* wqkvT = (u16*)(ws + (16u<<20));
  u16* woT   = (u16*)(ws + (22u<<20));
  u16* qb    = (u16*)(ws + (24u<<20));
  u16* kb    = (u16*)(ws + (40u<<20));
  u16* vT    = (u16*)(ws + (56u<<20));
  u16* ob    = xb;   // reuse xb after gemm_qkv

  conv_k    <<<dim3(5120), dim3(256), 0, stream>>>(x, wq, wk, wv, wo, xb, wqkvT, woT);
  gemm_qkv_k<<<dim3(64,24), dim3(256), 0, stream>>>(xb, wqkvT, qb, kb, vT);
  attn_k    <<<dim3(32,8), dim3(512), 0, stream>>>(qb, kb, vT, ob);
  gemm_out_k<<<dim3(64,8),  dim3(256), 0, stream>>>(ob, woT, out);
}

// Round 10
// 256.975 us; speedup vs baseline: 1.0198x; 1.0149x over previous
//
#include <hip/hip_runtime.h>
#include <hip/hip_bf16.h>
#include <math.h>

typedef unsigned short u16;
typedef unsigned int u32;
typedef __attribute__((ext_vector_type(8))) short bf16x8;   // 8 bf16 = 4 VGPRs
typedef __attribute__((ext_vector_type(4))) float f32x4;
typedef __attribute__((ext_vector_type(16))) float f32x16;

#define MFMA16(a,b,c) __builtin_amdgcn_mfma_f32_16x16x32_bf16(a,b,c,0,0,0)
#define MFMA32(a,b,c) __builtin_amdgcn_mfma_f32_32x32x16_bf16(a,b,c,0,0,0)

__device__ __forceinline__ u16 f2b(float f){
  unsigned u = __float_as_uint(f);
  u += 0x7fffu + ((u >> 16) & 1u);      // RNE
  return (u16)(u >> 16);
}
__device__ __forceinline__ u32 pack2(float a, float b){
  return (u32)f2b(a) | ((u32)f2b(b) << 16);
}
// packed f32x2 -> bf16x2 (RNE), single VALU op
__device__ __forceinline__ u32 cvtpk(float lo, float hi){
  u32 r; asm("v_cvt_pk_bf16_f32 %0, %1, %2" : "=v"(r) : "v"(lo), "v"(hi)); return r;
}

// async global->LDS, 16B per lane; LDS dest = wave-uniform base + lane*16
__device__ __forceinline__ void gll16(const void* g, void* l){
  __builtin_amdgcn_global_load_lds(
      (__attribute__((address_space(1))) void*)(const_cast<void*>(g)),
      (__attribute__((address_space(3))) void*)l, 16, 0, 0);
}

// ---------------- merged conversions ----------------
// blocks [0,4096): x -> bf16.  blocks [4096,5120): transpose-convert weights.
__global__ __launch_bounds__(256) void conv_k(
    const float* __restrict__ x,  const float* __restrict__ wq,
    const float* __restrict__ wk, const float* __restrict__ wv,
    const float* __restrict__ wo, u16* __restrict__ xb,
    u16* __restrict__ wqkvT, u16* __restrict__ woT)
{
  const int bid = blockIdx.x;
  if (bid < 4096){
    size_t i = ((size_t)bid*256 + threadIdx.x)*8;
    float4 a = *(const float4*)(x+i);
    float4 b = *(const float4*)(x+i+4);
    uint4 u;
    u.x = pack2(a.x, a.y);
    u.y = pack2(a.z, a.w);
    u.z = pack2(b.x, b.y);
    u.w = pack2(b.z, b.w);
    *(uint4*)(xb+i) = u;
    return;
  }
  const int id = bid - 4096;            // 0..1023
  const int z = id >> 8, rem = id & 255, i = rem >> 4, j = rem & 15;
  const float* src = (z==0)?wq:(z==1)?wk:(z==2)?wv:wo;
  u16* dst = (z<3) ? (wqkvT + (size_t)z*1024*1024) : woT;
  __shared__ u16 tile[64][72];
  const int t = threadIdx.x;
  const int cr = t >> 4, cc4 = (t & 15) * 4;
#pragma unroll
  for (int rr = 0; rr < 4; rr++){
    int r = rr*16 + cr;
    float4 v = *(const float4*)(src + (size_t)(i*64 + r)*1024 + j*64 + cc4);
    tile[cc4+0][r] = f2b(v.x);
    tile[cc4+1][r] = f2b(v.y);
    tile[cc4+2][r] = f2b(v.z);
    tile[cc4+3][r] = f2b(v.w);
  }
  __syncthreads();
  const int ro = t >> 2, co = (t & 3) * 16;
  uint4 a = *(uint4*)&tile[ro][co];
  uint4 b = *(uint4*)&tile[ro][co+8];
  u16* p = dst + (size_t)(j*64 + ro)*1024 + i*64 + co;
  *(uint4*)p = a;
  *(uint4*)(p+8) = b;
}

// ---------------- 128x128 bf16 GEMM mainloop (4 waves), BK=64 ----------------
// LDS row = 64 u16 (8 chunks of 8); chunk slot = ch ^ (row&7). 16 iters at K=1024.
__device__ __forceinline__ void gemm128_bt(
    const u16* __restrict__ A, const u16* __restrict__ B, int K,
    int rowBase, int colBase, f32x4 acc[4][4])
{
  __shared__ __align__(16) u16 lA[128*64];
  __shared__ __align__(16) u16 lB[128*64];
  const int tid = threadIdx.x, lane = tid & 63, wave = tid >> 6;
  const int wr = wave >> 1, wc = wave & 1;
  const int qd = lane >> 4, c = lane & 15;

  int aOff[4], bOff[4];                 // kb=1 offset = kb0 ^ 32
#pragma unroll
  for (int mi=0;mi<4;mi++){ int row = wr*64 + mi*16 + c; aOff[mi] = row*64 + ((qd ^ (row&7))*8); }
#pragma unroll
  for (int ni=0;ni<4;ni++){ int row = wc*64 + ni*16 + c; bOff[ni] = row*64 + ((qd ^ (row&7))*8); }

  const u16* gA[4]; const u16* gB[4]; int seg[4];
#pragma unroll
  for (int cc=0;cc<4;cc++){
    int s = wave*4 + cc;
    int row = s*8 + (lane>>3);
    int gch = (lane&7) ^ (row&7);
    gA[cc] = A + (size_t)(rowBase+row)*K + gch*8;
    gB[cc] = B + (size_t)(colBase+row)*K + gch*8;
    seg[cc] = s*512;
  }
#pragma unroll
  for (int mi=0;mi<4;mi++)
#pragma unroll
    for (int ni=0;ni<4;ni++)
#pragma unroll
      for (int e=0;e<4;e++) acc[mi][ni][e]=0.f;

  for (int k0=0; k0<K; k0+=64){
#pragma unroll
    for (int cc=0;cc<4;cc++){
      gll16(gA[cc] + k0, &lA[seg[cc]]);
      gll16(gB[cc] + k0, &lB[seg[cc]]);
    }
    __syncthreads();
#pragma unroll
    for (int kb=0; kb<2; kb++){
      const int x = kb*32;
      bf16x8 af[4], bb[4];
#pragma unroll
      for (int mi=0;mi<4;mi++) af[mi] = *(const bf16x8*)(lA + (aOff[mi]^x));
#pragma unroll
      for (int ni=0;ni<4;ni++) bb[ni] = *(const bf16x8*)(lB + (bOff[ni]^x));
#pragma unroll
      for (int ni=0;ni<4;ni++)
#pragma unroll
        for (int mi=0;mi<4;mi++)
          acc[mi][ni] = MFMA16(af[mi], bb[ni], acc[mi][ni]);
    }
    __syncthreads();
  }
}

// ---------------- 256x128 bf16 GEMM mainloop (8 waves, 512 thr), BK=64 --------
// Same per-wave 64x64 output as gemm128_bt (acc[4][4]) but 2x rows per block:
// barrier/drain + staging-issue cost per FLOP halves vs the 128^2 tile.
// LDS 48 KB -> 2 blocks/CU at <=128 VGPR (pinned via launch_bounds(512,4)).
__device__ __forceinline__ void gemm256_bt(
    const u16* __restrict__ A, const u16* __restrict__ B, int K,
    int rowBase, int colBase, f32x4 acc[4][4])
{
  __shared__ __align__(16) u16 lA[256*64];   // 32 KB
  __shared__ __align__(16) u16 lB[128*64];   // 16 KB
  const int tid = threadIdx.x, lane = tid & 63, wave = tid >> 6;
  const int wr = wave >> 1, wc = wave & 1;   // wr 0..3 (rows), wc 0..1 (cols)
  const int qd = lane >> 4, c = lane & 15;

  int aOff[4], bOff[4];                 // kb=1 offset = kb0 ^ 32
#pragma unroll
  for (int mi=0;mi<4;mi++){ int row = wr*64 + mi*16 + c; aOff[mi] = row*64 + ((qd ^ (row&7))*8); }
#pragma unroll
  for (int ni=0;ni<4;ni++){ int row = wc*64 + ni*16 + c; bOff[ni] = row*64 + ((qd ^ (row&7))*8); }

  const u16* gA[4]; int segA[4];        // A: 32 segs of 1KB, 4 per wave
#pragma unroll
  for (int cc=0;cc<4;cc++){
    int s = wave*4 + cc;                // 0..31
    int row = s*8 + (lane>>3);          // 0..255
    int gch = (lane&7) ^ (row&7);
    gA[cc] = A + (size_t)(rowBase+row)*K + gch*8;
    segA[cc] = s*512;
  }
  const u16* gB[2]; int segB[2];        // B: 16 segs, 2 per wave
#pragma unroll
  for (int cc=0;cc<2;cc++){
    int s = wave*2 + cc;                // 0..15
    int row = s*8 + (lane>>3);          // 0..127
    int gch = (lane&7) ^ (row&7);
    gB[cc] = B + (size_t)(colBase+row)*K + gch*8;
    segB[cc] = s*512;
  }
#pragma unroll
  for (int mi=0;mi<4;mi++)
#pragma unroll
    for (int ni=0;ni<4;ni++)
#pragma unroll
      for (int e=0;e<4;e++) acc[mi][ni][e]=0.f;

  for (int k0=0; k0<K; k0+=64){
#pragma unroll
    for (int cc=0;cc<4;cc++) gll16(gA[cc] + k0, &lA[segA[cc]]);
#pragma unroll
    for (int cc=0;cc<2;cc++) gll16(gB[cc] + k0, &lB[segB[cc]]);
    __syncthreads();
#pragma unroll
    for (int kb=0; kb<2; kb++){
      const int x = kb*32;
      bf16x8 af[4], bb[4];
#pragma unroll
      for (int mi=0;mi<4;mi++) af[mi] = *(const bf16x8*)(lA + (aOff[mi]^x));
#pragma unroll
      for (int ni=0;ni<4;ni++) bb[ni] = *(const bf16x8*)(lB + (bOff[ni]^x));
#pragma unroll
      for (int ni=0;ni<4;ni++)
#pragma unroll
        for (int mi=0;mi<4;mi++)
          acc[mi][ni] = MFMA16(af[mi], bb[ni], acc[mi][ni]);
    }
    __syncthreads();
  }
}

// ---------------- QKV GEMM + RoPE epilogue (256x128 tile, 512 thr) -----------
// q pre-scaled by QSC = log2(e)/128 so attention uses exp2 directly.
// RoPE'd dims stored INTERLEAVED: d' = 2j   -> rotated-even of pair j,
//                                 d' = 2j+1 -> rotated-odd  of pair j  (j in [0,32)).
// d' in [64,128) = pass-through. Same permutation for q and k => dot products exact.
// V stored as [bh][t/4][d][4]  ("v4" layout).
#define QSC (1.44269504088896f/128.0f)
__global__ __launch_bounds__(512, 4) void gemm_qkv_k(
    const u16* __restrict__ xb, const u16* __restrict__ wqkvT,
    u16* __restrict__ q, u16* __restrict__ k, u16* __restrict__ vT)
{
  f32x4 acc[4][4];
  const int rowBase = blockIdx.x*256, colBase = blockIdx.y*128;
  gemm256_bt(xb, wqkvT, 1024, rowBase, colBase, acc);
  const int tid = threadIdx.x, lane = tid & 63, wave = tid >> 6;
  const int wr = wave >> 1, wc = wave & 1;
  const int qd = lane >> 4, c = lane & 15;
  const int nb = blockIdx.y;
  const int proj = nb >> 3, h = nb & 7;

  if (proj < 2){
    u16* dst = (proj==0) ? q : k;
    const float os = (proj==0) ? QSC : 1.0f;
    if (wc == 0){
      // pairs j=c (tiles 0,2) and j=c+16 (tiles 1,3)
      float ang0 = __powf(10000.0f, -(float)c      * (1.0f/32.0f));
      float ang1 = __powf(10000.0f, -(float)(c+16) * (1.0f/32.0f));
#pragma unroll
      for (int mi=0;mi<4;mi++){
#pragma unroll
        for (int r=0;r<4;r++){
          int row = rowBase + wr*64 + mi*16 + qd*4 + r;
          int b = row >> 11, t = row & 2047;
          u32* dst32 = (u32*)(dst + (((long)(b*8+h))*2048 + t)*128);
          float s0,c0,s1,c1;
          __sincosf((float)t*ang0, &s0, &c0);
          __sincosf((float)t*ang1, &s1, &c1);
          { float e = acc[mi][0][r], od = acc[mi][2][r];
            dst32[c]      = pack2((e*c0 - od*s0)*os, (e*s0 + od*c0)*os); }
          { float e = acc[mi][1][r], od = acc[mi][3][r];
            dst32[16 + c] = pack2((e*c1 - od*s1)*os, (e*s1 + od*c1)*os); }
        }
      }
    } else {
      // pass-through half d in [64,128)
#pragma unroll
      for (int mi=0;mi<4;mi++){
#pragma unroll
        for (int r=0;r<4;r++){
          int row = rowBase + wr*64 + mi*16 + qd*4 + r;
          int b = row >> 11, t = row & 2047;
          long base = (((long)(b*8+h))*2048 + t)*128 + 64;
#pragma unroll
          for (int ni=0;ni<4;ni++)
            dst[base + ni*16 + c] = f2b(acc[mi][ni][r]*os);
        }
      }
    }
  } else {
    // v: [bh][t/4][d][4]; acc[mi][ni][0..3] = 4 consecutive t at one d.
#pragma unroll
    for (int mi=0;mi<4;mi++){
      int row0 = rowBase + wr*64 + mi*16 + qd*4;
      int b = row0 >> 11, t = row0 & 2047;
      long base = ((long)(b*8+h)*512 + (t>>2)) * 512;   // *(128 d * 4)
#pragma unroll
      for (int ni=0;ni<4;ni++){
        int d = wc*64 + ni*16 + c;
        *(uint2*)(vT + base + d*4) = make_uint2(pack2(acc[mi][ni][0], acc[mi][ni][1]),
                                                pack2(acc[mi][ni][2], acc[mi][ni][3]));
      }
    }
  }
}

// ---------------- flash attention (r4 version, best measured: 73.8 us) --------
// 256 blocks x 512 thr, heavy+light sub pairing, KVBLK=64, 1 block/CU.
// T12: P fully in-register via cvt_pk_bf16 + permlane32_swap (HW-verified r3).
// launch_bounds(512,2): the 128-VGPR allocation fits this body (WRITE=o only).
// r5-r8 lessons: occupancy/iter-count/pipeline variants all lose to this at the
// immovable 128-VGPR budget.
// K in LDS [2][64 key][128 d] swiz ^(row&15); V in LDS [2][16 t4][128 d][4] linear.
__global__ __launch_bounds__(512, 2) void attn_k(
    const u16* __restrict__ q, const u16* __restrict__ k,
    const u16* __restrict__ vT, u16* __restrict__ o)
{
  __shared__ __align__(16) u16 smem[33280];        // 65 KB
  u16* lK = smem;                                  // [2][64 key][128 d], swiz ^(row&15)
  u16* lV = smem + 16384;                          // [2][16 t4][128 d][4], linear
  float* scrO = (float*)smem;                      // epilogue [16][32][32] f32 = 64KB
  float* scrL = (float*)(smem + 32768);            // epilogue [2][128] (bytes 64K..65K)

  const int tid = threadIdx.x, lane = tid & 63, wave = tid >> 6;
  const int h2 = lane >> 5, ln = lane & 31;
  const int qs = wave >> 1, kh = wave & 1;
  const int bh = blockIdx.x, p = blockIdx.y;

  auto loadKV = [&](int kt, int buf){
    const u16* kSrc = k + ((long)bh*2048 + kt*64)*128;
#pragma unroll
    for (int cc=0; cc<2; cc++){
      int s = wave*2+cc;
      int row = s*4 + (lane>>4);
      int gch = (lane&15) ^ (row&15);
      gll16(kSrc + row*128 + gch*8, lK + buf*8192 + s*512);
    }
    const u16* vSrc = vT + (long)bh*262144 + (long)kt*8192;   // 16KB tile, contiguous
#pragma unroll
    for (int cc=0; cc<2; cc++){
      int s = wave*2+cc;
      gll16(vSrc + s*512 + lane*8, lV + buf*8192 + s*512);
    }
  };

  for (int sub=0; sub<2; sub++){
    const int qt = sub ? (15 - p) : p;
    const int q0 = qt*128;
    const int qw = q0 + qs*32;          // wave's q-strip base

    bf16x8 aQ[8];
    {
      const long qrow = (long)bh*2048 + qw + ln;
#pragma unroll
      for (int ch=0; ch<8; ch++)
        aQ[ch] = *(const bf16x8*)(q + qrow*128 + ch*16 + h2*8);
    }
    f32x16 accO[4];
#pragma unroll
    for (int dt=0; dt<4; dt++)
#pragma unroll
      for (int r=0;r<16;r++) accO[dt][r] = 0.f;
    float lsum = 0.f;

    __syncthreads();                    // prior sub's LDS users done
    loadKV(0, 0);
    int cur = 0;
    const int ktMax = 2*qt + 1;

    for (int kt=0; kt<=ktMax; kt++){
      __syncthreads();                  // buf[cur] ready; buf[cur^1] readers done
      if (kt < ktMax) loadKV(kt+1, cur^1);

      const int key0 = kt*64 + kh*32;
      if (key0 <= qw + 31){             // not fully masked for this wave
        // S^T[key][q] 32x32: A = K-half, B = Q-strip
        f32x16 accS;
#pragma unroll
        for (int r=0;r<16;r++) accS[r] = 0.f;
        const int krow = kh*32 + ln;
#pragma unroll
        for (int ch=0; ch<8; ch++){
          bf16x8 ak = *(const bf16x8*)(lK + cur*8192 + krow*128 + (((ch*2+h2) ^ (krow&15))*8));
          accS = MFMA32(ak, aQ[ch], accS);
        }

        const bool diag = (key0 + 31 > qw);
        float pe[16];
        float ls0 = 0.f, ls1 = 0.f;
#pragma unroll
        for (int r=0;r<16;r++){
          float s = accS[r];
          if (diag){
            int keyg = key0 + (r&3) + 8*(r>>2) + 4*h2;
            if (keyg > qw + ln) s = -INFINITY;   // exp2(-inf) = 0
          }
          pe[r] = exp2f(s);
          if (r & 1) ls1 += pe[r]; else ls0 += pe[r];
        }
        lsum += ls0 + ls1;

        // ---- P -> MFMA A-fragments fully in-register (T12, verified r3) ----
        u32 w0 = cvtpk(pe[0],  pe[1]),  w1 = cvtpk(pe[2],  pe[3]);
        u32 w2 = cvtpk(pe[4],  pe[5]),  w3 = cvtpk(pe[6],  pe[7]);
        u32 w4 = cvtpk(pe[8],  pe[9]),  w5 = cvtpk(pe[10], pe[11]);
        u32 w6 = cvtpk(pe[12], pe[13]), w7 = cvtpk(pe[14], pe[15]);
        asm volatile("v_permlane32_swap_b32 %0, %1" : "+v"(w0), "+v"(w2));
        asm volatile("v_permlane32_swap_b32 %0, %1" : "+v"(w1), "+v"(w3));
        asm volatile("v_permlane32_swap_b32 %0, %1" : "+v"(w4), "+v"(w6));
        asm volatile("v_permlane32_swap_b32 %0, %1" : "+v"(w5), "+v"(w7));
        union { bf16x8 v; u32 u[4]; } ap0, ap1;
        ap0.u[0]=w0; ap0.u[1]=w1; ap0.u[2]=w2; ap0.u[3]=w3;   // keys key0+ 0..15
        ap1.u[0]=w4; ap1.u[1]=w5; ap1.u[2]=w6; ap1.u[3]=w7;   // keys key0+16..31

        // O[q][d] partial: A = P fragment, B = V (v4 layout)
#pragma unroll
        for (int kk=0; kk<2; kk++){
          bf16x8 ap = kk ? ap1.v : ap0.v;
          const int t4l = kh*8 + kk*4 + h2*2;   // 8-key group = 2 consecutive t4
#pragma unroll
          for (int dt=0; dt<4; dt++){
            int d = dt*32 + ln;
            const u16* vp = lV + cur*8192 + (t4l*128 + d)*4;
            union { bf16x8 v; uint2 u[2]; } bb;
            bb.u[0] = *(const uint2*)(vp);
            bb.u[1] = *(const uint2*)(vp + 512);
            accO[dt] = MFMA32(ap, bb.v, accO[dt]);
          }
        }
      }
      cur ^= 1;
    }

    // ---- epilogue: combine kh halves, normalize, store ----
    lsum += __shfl_xor(lsum, 32);       // fold h2 halves
    __syncthreads();                    // main-loop LDS reads done before alias reuse
    if (kh == 1){
#pragma unroll
      for (int dt=0; dt<4; dt++)
#pragma unroll
        for (int r=0;r<16;r++){
          int row = (r&3) + 8*(r>>2) + 4*h2;
          scrO[((qs*4+dt)*32 + row)*32 + ln] = accO[dt][r];
        }
      if (h2 == 0) scrL[128 + qs*32 + ln] = lsum;
    } else {
      if (h2 == 0) scrL[qs*32 + ln] = lsum;
    }
    __syncthreads();
    if (kh == 0){
      float linv[16];
#pragma unroll
      for (int r=0;r<16;r++){
        int row = (r&3) + 8*(r>>2) + 4*h2;
        linv[r] = 1.0f / (scrL[qs*32 + row] + scrL[128 + qs*32 + row]);
      }
      const int b = bh >> 3, h = bh & 7;
#pragma unroll
      for (int dt=0; dt<4; dt++){
#pragma unroll
        for (int r=0;r<16;r++){
          int row = (r&3) + 8*(r>>2) + 4*h2;
          float val = accO[dt][r] + scrO[((qs*4+dt)*32 + row)*32 + ln];
          int t = q0 + qs*32 + row;
          o[((long)(b*2048 + t))*1024 + h*128 + dt*32 + ln] = f2b(val * linv[r]);
        }
      }
    }
  }
}

// ---------------- output projection ----------------
__global__ __launch_bounds__(256) void gemm_out_k(
    const u16* __restrict__ oa, const u16* __restrict__ woT, float* __restrict__ out)
{
  f32x4 acc[4][4];
  const int rowBase = blockIdx.x*128, colBase = blockIdx.y*128;
  gemm128_bt(oa, woT, 1024, rowBase, colBase, acc);
  const int lane = threadIdx.x & 63, wave = threadIdx.x >> 6;
  const int wr = wave >> 1, wc = wave & 1;
  const int qd = lane >> 4, c = lane & 15;
#pragma unroll
  for (int mi=0;mi<4;mi++){
#pragma unroll
    for (int ni=0;ni<4;ni++){
      int row = rowBase + wr*64 + mi*16 + qd*4;
      int col = colBase + wc*64 + ni*16 + c;
#pragma unroll
      for (int r=0;r<4;r++)
        out[(size_t)(row+r)*1024 + col] = acc[mi][ni][r];
    }
  }
}

extern "C" void kernel_launch(void* const* d_in, const int* in_sizes, int n_in,
                              void* d_out, int out_size, void* d_ws, size_t ws_size,
                              hipStream_t stream) {
  const float* x  = (const float*)d_in[0];
  const float* wq = (const float*)d_in[1];
  const float* wk = (const float*)d_in[2];
  const float* wv = (const float*)d_in[3];
  const float* wo = (const float*)d_in[4];
  float* out = (float*)d_out;

  char* ws = (char*)d_ws;
  u16* xb    = (u16*)(ws);
  u16* wqkvT = (u16*)(ws + (16u<<20));
  u16* woT   = (u16*)(ws + (22u<<20));
  u16* qb    = (u16*)(ws + (24u<<20));
  u16* kb    = (u16*)(ws + (40u<<20));
  u16* vT    = (u16*)(ws + (56u<<20));
  u16* ob    = xb;   // reuse xb after gemm_qkv

  conv_k    <<<dim3(5120), dim3(256), 0, stream>>>(x, wq, wk, wv, wo, xb, wqkvT, woT);
  gemm_qkv_k<<<dim3(32,24), dim3(512), 0, stream>>>(xb, wqkvT, qb, kb, vT);
  attn_k    <<<dim3(32,8), dim3(512), 0, stream>>>(qb, kb, vT, ob);
  gemm_out_k<<<dim3(64,8),  dim3(256), 0, stream>>>(ob, woT, out);
}

// Round 11
// 238.932 us; speedup vs baseline: 1.0968x; 1.0755x over previous
//
#include <hip/hip_runtime.h>
#include <hip/hip_bf16.h>
#include <math.h>

typedef unsigned short u16;
typedef unsigned int u32;
typedef __attribute__((ext_vector_type(8))) short bf16x8;   // 8 bf16 = 4 VGPRs
typedef __attribute__((ext_vector_type(4))) float f32x4;
typedef __attribute__((ext_vector_type(16))) float f32x16;

#define MFMA16(a,b,c) __builtin_amdgcn_mfma_f32_16x16x32_bf16(a,b,c,0,0,0)
#define MFMA32(a,b,c) __builtin_amdgcn_mfma_f32_32x32x16_bf16(a,b,c,0,0,0)

__device__ __forceinline__ u16 f2b(float f){
  unsigned u = __float_as_uint(f);
  u += 0x7fffu + ((u >> 16) & 1u);      // RNE
  return (u16)(u >> 16);
}
__device__ __forceinline__ u32 pack2(float a, float b){
  return (u32)f2b(a) | ((u32)f2b(b) << 16);
}
// packed f32x2 -> bf16x2 (RNE), single VALU op
__device__ __forceinline__ u32 cvtpk(float lo, float hi){
  u32 r; asm("v_cvt_pk_bf16_f32 %0, %1, %2" : "=v"(r) : "v"(lo), "v"(hi)); return r;
}

// async global->LDS, 16B per lane; LDS dest = wave-uniform base + lane*16
__device__ __forceinline__ void gll16(const void* g, void* l){
  __builtin_amdgcn_global_load_lds(
      (__attribute__((address_space(1))) void*)(const_cast<void*>(g)),
      (__attribute__((address_space(3))) void*)l, 16, 0, 0);
}

// ---------------- merged conversions ----------------
// blocks [0,4096): x -> bf16.  blocks [4096,5120): transpose-convert weights.
__global__ __launch_bounds__(256) void conv_k(
    const float* __restrict__ x,  const float* __restrict__ wq,
    const float* __restrict__ wk, const float* __restrict__ wv,
    const float* __restrict__ wo, u16* __restrict__ xb,
    u16* __restrict__ wqkvT, u16* __restrict__ woT)
{
  const int bid = blockIdx.x;
  if (bid < 4096){
    size_t i = ((size_t)bid*256 + threadIdx.x)*8;
    float4 a = *(const float4*)(x+i);
    float4 b = *(const float4*)(x+i+4);
    uint4 u;
    u.x = pack2(a.x, a.y);
    u.y = pack2(a.z, a.w);
    u.z = pack2(b.x, b.y);
    u.w = pack2(b.z, b.w);
    *(uint4*)(xb+i) = u;
    return;
  }
  const int id = bid - 4096;            // 0..1023
  const int z = id >> 8, rem = id & 255, i = rem >> 4, j = rem & 15;
  const float* src = (z==0)?wq:(z==1)?wk:(z==2)?wv:wo;
  u16* dst = (z<3) ? (wqkvT + (size_t)z*1024*1024) : woT;
  __shared__ u16 tile[64][72];
  const int t = threadIdx.x;
  const int cr = t >> 4, cc4 = (t & 15) * 4;
#pragma unroll
  for (int rr = 0; rr < 4; rr++){
    int r = rr*16 + cr;
    float4 v = *(const float4*)(src + (size_t)(i*64 + r)*1024 + j*64 + cc4);
    tile[cc4+0][r] = f2b(v.x);
    tile[cc4+1][r] = f2b(v.y);
    tile[cc4+2][r] = f2b(v.z);
    tile[cc4+3][r] = f2b(v.w);
  }
  __syncthreads();
  const int ro = t >> 2, co = (t & 3) * 16;
  uint4 a = *(uint4*)&tile[ro][co];
  uint4 b = *(uint4*)&tile[ro][co+8];
  u16* p = dst + (size_t)(j*64 + ro)*1024 + i*64 + co;
  *(uint4*)p = a;
  *(uint4*)(p+8) = b;
}

// ---------------- 128x128 bf16 GEMM mainloop, BK=64, C = A[M][K] * B[N][K]^T ------
// LDS row = 64 u16 (8 chunks of 8); chunk slot = ch ^ (row&7). 16 iters at K=1024.
// r10 lesson: 256-row tile (8-wave barriers, 2 blocks/CU) was SLOWER than this
// 4-wave structure with 6-deep backfill -- wider barriers lose.
__device__ __forceinline__ void gemm128_bt(
    const u16* __restrict__ A, const u16* __restrict__ B, int K,
    int rowBase, int colBase, f32x4 acc[4][4])
{
  __shared__ __align__(16) u16 lA[128*64];
  __shared__ __align__(16) u16 lB[128*64];
  const int tid = threadIdx.x, lane = tid & 63, wave = tid >> 6;
  const int wr = wave >> 1, wc = wave & 1;
  const int qd = lane >> 4, c = lane & 15;

  int aOff[4], bOff[4];                 // kb=1 offset = kb0 ^ 32
#pragma unroll
  for (int mi=0;mi<4;mi++){ int row = wr*64 + mi*16 + c; aOff[mi] = row*64 + ((qd ^ (row&7))*8); }
#pragma unroll
  for (int ni=0;ni<4;ni++){ int row = wc*64 + ni*16 + c; bOff[ni] = row*64 + ((qd ^ (row&7))*8); }

  const u16* gA[4]; const u16* gB[4]; int seg[4];
#pragma unroll
  for (int cc=0;cc<4;cc++){
    int s = wave*4 + cc;
    int row = s*8 + (lane>>3);
    int gch = (lane&7) ^ (row&7);
    gA[cc] = A + (size_t)(rowBase+row)*K + gch*8;
    gB[cc] = B + (size_t)(colBase+row)*K + gch*8;
    seg[cc] = s*512;
  }
#pragma unroll
  for (int mi=0;mi<4;mi++)
#pragma unroll
    for (int ni=0;ni<4;ni++)
#pragma unroll
      for (int e=0;e<4;e++) acc[mi][ni][e]=0.f;

  for (int k0=0; k0<K; k0+=64){
#pragma unroll
    for (int cc=0;cc<4;cc++){
      gll16(gA[cc] + k0, &lA[seg[cc]]);
      gll16(gB[cc] + k0, &lB[seg[cc]]);
    }
    __syncthreads();
#pragma unroll
    for (int kb=0; kb<2; kb++){
      const int x = kb*32;
      bf16x8 af[4], bb[4];
#pragma unroll
      for (int mi=0;mi<4;mi++) af[mi] = *(const bf16x8*)(lA + (aOff[mi]^x));
#pragma unroll
      for (int ni=0;ni<4;ni++) bb[ni] = *(const bf16x8*)(lB + (bOff[ni]^x));
#pragma unroll
      for (int ni=0;ni<4;ni++)
#pragma unroll
        for (int mi=0;mi<4;mi++)
          acc[mi][ni] = MFMA16(af[mi], bb[ni], acc[mi][ni]);
    }
    __syncthreads();
  }
}

// ---------------- QKV GEMM + RoPE epilogue ----------------
// q pre-scaled by QSC = log2(e)/128 so attention uses exp2 directly.
// RoPE'd dims stored INTERLEAVED: d' = 2j   -> rotated-even of pair j,
//                                 d' = 2j+1 -> rotated-odd  of pair j  (j in [0,32)).
// d' in [64,128) = pass-through. Same permutation for q and k => dot products exact.
// V stored as [bh][t/4][d][4]  ("v4" layout): thread's 4 consecutive-t accs land
// contiguous; lanes adjacent in d -> 4x128B segments per store.
#define QSC (1.44269504088896f/128.0f)
__global__ __launch_bounds__(256) void gemm_qkv_k(
    const u16* __restrict__ xb, const u16* __restrict__ wqkvT,
    u16* __restrict__ q, u16* __restrict__ k, u16* __restrict__ vT)
{
  f32x4 acc[4][4];
  const int rowBase = blockIdx.x*128, colBase = blockIdx.y*128;
  gemm128_bt(xb, wqkvT, 1024, rowBase, colBase, acc);
  const int tid = threadIdx.x, lane = tid & 63, wave = tid >> 6;
  const int wr = wave >> 1, wc = wave & 1;
  const int qd = lane >> 4, c = lane & 15;
  const int nb = blockIdx.y;
  const int proj = nb >> 3, h = nb & 7;

  if (proj < 2){
    u16* dst = (proj==0) ? q : k;
    const float os = (proj==0) ? QSC : 1.0f;
    if (wc == 0){
      // pairs j=c (tiles 0,2) and j=c+16 (tiles 1,3)
      float ang0 = __powf(10000.0f, -(float)c      * (1.0f/32.0f));
      float ang1 = __powf(10000.0f, -(float)(c+16) * (1.0f/32.0f));
#pragma unroll
      for (int mi=0;mi<4;mi++){
#pragma unroll
        for (int r=0;r<4;r++){
          int row = rowBase + wr*64 + mi*16 + qd*4 + r;
          int b = row >> 11, t = row & 2047;
          u32* dst32 = (u32*)(dst + (((long)(b*8+h))*2048 + t)*128);
          float s0,c0,s1,c1;
          __sincosf((float)t*ang0, &s0, &c0);
          __sincosf((float)t*ang1, &s1, &c1);
          { float e = acc[mi][0][r], od = acc[mi][2][r];
            dst32[c]      = pack2((e*c0 - od*s0)*os, (e*s0 + od*c0)*os); }
          { float e = acc[mi][1][r], od = acc[mi][3][r];
            dst32[16 + c] = pack2((e*c1 - od*s1)*os, (e*s1 + od*c1)*os); }
        }
      }
    } else {
      // pass-through half d in [64,128)
#pragma unroll
      for (int mi=0;mi<4;mi++){
#pragma unroll
        for (int r=0;r<4;r++){
          int row = rowBase + wr*64 + mi*16 + qd*4 + r;
          int b = row >> 11, t = row & 2047;
          long base = (((long)(b*8+h))*2048 + t)*128 + 64;
#pragma unroll
          for (int ni=0;ni<4;ni++)
            dst[base + ni*16 + c] = f2b(acc[mi][ni][r]*os);
        }
      }
    }
  } else {
    // v: [bh][t/4][d][4]; acc[mi][ni][0..3] = 4 consecutive t at one d.
#pragma unroll
    for (int mi=0;mi<4;mi++){
      int row0 = rowBase + wr*64 + mi*16 + qd*4;
      int b = row0 >> 11, t = row0 & 2047;
      long base = ((long)(b*8+h)*512 + (t>>2)) * 512;   // *(128 d * 4)
#pragma unroll
      for (int ni=0;ni<4;ni++){
        int d = wc*64 + ni*16 + c;
        *(uint2*)(vT + base + d*4) = make_uint2(pack2(acc[mi][ni][0], acc[mi][ni][1]),
                                                pack2(acc[mi][ni][2], acc[mi][ni][3]));
      }
    }
  }
}

// ---------------- flash attention (r4 + split-accS) ----------------
// 256 blocks x 512 thr, heavy+light sub pairing, KVBLK=64, 1 block/CU.
// T12: P fully in-register via cvt_pk_bf16 + permlane32_swap (HW-verified r3).
// NEW (r11): QK accumulation split into two independent 4-MFMA chains s0/s1
// (interleaved issue) -> dependent-MFMA spacing 2x, chain latency ~halved.
// +16 VGPR; spill alarm = WRITE_SIZE > 20 MB.
// K in LDS [2][64 key][128 d] swiz ^(row&15); V in LDS [2][16 t4][128 d][4] linear.
__global__ __launch_bounds__(512, 2) void attn_k(
    const u16* __restrict__ q, const u16* __restrict__ k,
    const u16* __restrict__ vT, u16* __restrict__ o)
{
  __shared__ __align__(16) u16 smem[33280];        // 65 KB
  u16* lK = smem;                                  // [2][64 key][128 d], swiz ^(row&15)
  u16* lV = smem + 16384;                          // [2][16 t4][128 d][4], linear
  float* scrO = (float*)smem;                      // epilogue [16][32][32] f32 = 64KB
  float* scrL = (float*)(smem + 32768);            // epilogue [2][128] (bytes 64K..65K)

  const int tid = threadIdx.x, lane = tid & 63, wave = tid >> 6;
  const int h2 = lane >> 5, ln = lane & 31;
  const int qs = wave >> 1, kh = wave & 1;
  const int bh = blockIdx.x, p = blockIdx.y;

  auto loadKV = [&](int kt, int buf){
    const u16* kSrc = k + ((long)bh*2048 + kt*64)*128;
#pragma unroll
    for (int cc=0; cc<2; cc++){
      int s = wave*2+cc;
      int row = s*4 + (lane>>4);
      int gch = (lane&15) ^ (row&15);
      gll16(kSrc + row*128 + gch*8, lK + buf*8192 + s*512);
    }
    const u16* vSrc = vT + (long)bh*262144 + (long)kt*8192;   // 16KB tile, contiguous
#pragma unroll
    for (int cc=0; cc<2; cc++){
      int s = wave*2+cc;
      gll16(vSrc + s*512 + lane*8, lV + buf*8192 + s*512);
    }
  };

  for (int sub=0; sub<2; sub++){
    const int qt = sub ? (15 - p) : p;
    const int q0 = qt*128;
    const int qw = q0 + qs*32;          // wave's q-strip base

    bf16x8 aQ[8];
    {
      const long qrow = (long)bh*2048 + qw + ln;
#pragma unroll
      for (int ch=0; ch<8; ch++)
        aQ[ch] = *(const bf16x8*)(q + qrow*128 + ch*16 + h2*8);
    }
    f32x16 accO[4];
#pragma unroll
    for (int dt=0; dt<4; dt++)
#pragma unroll
      for (int r=0;r<16;r++) accO[dt][r] = 0.f;
    float lsum = 0.f;

    __syncthreads();                    // prior sub's LDS users done
    loadKV(0, 0);
    int cur = 0;
    const int ktMax = 2*qt + 1;

    for (int kt=0; kt<=ktMax; kt++){
      __syncthreads();                  // buf[cur] ready; buf[cur^1] readers done
      if (kt < ktMax) loadKV(kt+1, cur^1);

      const int key0 = kt*64 + kh*32;
      if (key0 <= qw + 31){             // not fully masked for this wave
        // S^T[key][q] 32x32: A = K-half, B = Q-strip.
        // Two independent accumulation chains, interleaved issue (r11).
        f32x16 s0v, s1v;
#pragma unroll
        for (int r=0;r<16;r++){ s0v[r]=0.f; s1v[r]=0.f; }
        const int krow = kh*32 + ln;
#pragma unroll
        for (int ch=0; ch<4; ch++){
          bf16x8 ak0 = *(const bf16x8*)(lK + cur*8192 + krow*128 + ((((ch  )*2+h2) ^ (krow&15))*8));
          bf16x8 ak1 = *(const bf16x8*)(lK + cur*8192 + krow*128 + ((((ch+4)*2+h2) ^ (krow&15))*8));
          s0v = MFMA32(ak0, aQ[ch],   s0v);
          s1v = MFMA32(ak1, aQ[ch+4], s1v);
        }

        const bool diag = (key0 + 31 > qw);
        float pe[16];
        float ls0 = 0.f, ls1 = 0.f;
#pragma unroll
        for (int r=0;r<16;r++){
          float s = s0v[r] + s1v[r];
          if (diag){
            int keyg = key0 + (r&3) + 8*(r>>2) + 4*h2;
            if (keyg > qw + ln) s = -INFINITY;   // exp2(-inf) = 0
          }
          pe[r] = exp2f(s);
          if (r & 1) ls1 += pe[r]; else ls0 += pe[r];
        }
        lsum += ls0 + ls1;

        // ---- P -> MFMA A-fragments fully in-register (T12, verified r3) ----
        u32 w0 = cvtpk(pe[0],  pe[1]),  w1 = cvtpk(pe[2],  pe[3]);
        u32 w2 = cvtpk(pe[4],  pe[5]),  w3 = cvtpk(pe[6],  pe[7]);
        u32 w4 = cvtpk(pe[8],  pe[9]),  w5 = cvtpk(pe[10], pe[11]);
        u32 w6 = cvtpk(pe[12], pe[13]), w7 = cvtpk(pe[14], pe[15]);
        asm volatile("v_permlane32_swap_b32 %0, %1" : "+v"(w0), "+v"(w2));
        asm volatile("v_permlane32_swap_b32 %0, %1" : "+v"(w1), "+v"(w3));
        asm volatile("v_permlane32_swap_b32 %0, %1" : "+v"(w4), "+v"(w6));
        asm volatile("v_permlane32_swap_b32 %0, %1" : "+v"(w5), "+v"(w7));
        union { bf16x8 v; u32 u[4]; } ap0, ap1;
        ap0.u[0]=w0; ap0.u[1]=w1; ap0.u[2]=w2; ap0.u[3]=w3;   // keys key0+ 0..15
        ap1.u[0]=w4; ap1.u[1]=w5; ap1.u[2]=w6; ap1.u[3]=w7;   // keys key0+16..31

        // O[q][d] partial: A = P fragment, B = V (v4 layout)
#pragma unroll
        for (int kk=0; kk<2; kk++){
          bf16x8 ap = kk ? ap1.v : ap0.v;
          const int t4l = kh*8 + kk*4 + h2*2;   // 8-key group = 2 consecutive t4
#pragma unroll
          for (int dt=0; dt<4; dt++){
            int d = dt*32 + ln;
            const u16* vp = lV + cur*8192 + (t4l*128 + d)*4;
            union { bf16x8 v; uint2 u[2]; } bb;
            bb.u[0] = *(const uint2*)(vp);
            bb.u[1] = *(const uint2*)(vp + 512);
            accO[dt] = MFMA32(ap, bb.v, accO[dt]);
          }
        }
      }
      cur ^= 1;
    }

    // ---- epilogue: combine kh halves, normalize, store ----
    lsum += __shfl_xor(lsum, 32);       // fold h2 halves
    __syncthreads();                    // main-loop LDS reads done before alias reuse
    if (kh == 1){
#pragma unroll
      for (int dt=0; dt<4; dt++)
#pragma unroll
      for (int r=0;r<16;r++){
        int row = (r&3) + 8*(r>>2) + 4*h2;
        scrO[((qs*4+dt)*32 + row)*32 + ln] = accO[dt][r];
      }
      if (h2 == 0) scrL[128 + qs*32 + ln] = lsum;
    } else {
      if (h2 == 0) scrL[qs*32 + ln] = lsum;
    }
    __syncthreads();
    if (kh == 0){
      float linv[16];
#pragma unroll
      for (int r=0;r<16;r++){
        int row = (r&3) + 8*(r>>2) + 4*h2;
        linv[r] = 1.0f / (scrL[qs*32 + row] + scrL[128 + qs*32 + row]);
      }
      const int b = bh >> 3, h = bh & 7;
#pragma unroll
      for (int dt=0; dt<4; dt++){
#pragma unroll
        for (int r=0;r<16;r++){
          int row = (r&3) + 8*(r>>2) + 4*h2;
          float val = accO[dt][r] + scrO[((qs*4+dt)*32 + row)*32 + ln];
          int t = q0 + qs*32 + row;
          o[((long)(b*2048 + t))*1024 + h*128 + dt*32 + ln] = f2b(val * linv[r]);
        }
      }
    }
  }
}

// ---------------- output projection ----------------
__global__ __launch_bounds__(256) void gemm_out_k(
    const u16* __restrict__ oa, const u16* __restrict__ woT, float* __restrict__ out)
{
  f32x4 acc[4][4];
  const int rowBase = blockIdx.x*128, colBase = blockIdx.y*128;
  gemm128_bt(oa, woT, 1024, rowBase, colBase, acc);
  const int lane = threadIdx.x & 63, wave = threadIdx.x >> 6;
  const int wr = wave >> 1, wc = wave & 1;
  const int qd = lane >> 4, c = lane & 15;
#pragma unroll
  for (int mi=0;mi<4;mi++){
#pragma unroll
    for (int ni=0;ni<4;ni++){
      int row = rowBase + wr*64 + mi*16 + qd*4;
      int col = colBase + wc*64 + ni*16 + c;
#pragma unroll
      for (int r=0;r<4;r++)
        out[(size_t)(row+r)*1024 + col] = acc[mi][ni][r];
    }
  }
}

extern "C" void kernel_launch(void* const* d_in, const int* in_sizes, int n_in,
                              void* d_out, int out_size, void* d_ws, size_t ws_size,
                              hipStream_t stream) {
  const float* x  = (const float*)d_in[0];
  const float* wq = (const float*)d_in[1];
  const float* wk = (const float*)d_in[2];
  const float* wv = (const float*)d_in[3];
  const float* wo = (const float*)d_in[4];
  float* out = (float*)d_out;

  char* ws = (char*)d_ws;
  u16* xb    = (u16*)(ws);
  u16* wqkvT = (u16*)(ws + (16u<<20));
  u16* woT   = (u16*)(ws + (22u<<20));
  u16* qb    = (u16*)(ws + (24u<<20));
  u16* kb    = (u16*)(ws + (40u<<20));
  u16* vT    = (u16*)(ws + (56u<<20));
  u16* ob    = xb;   // reuse xb after gemm_qkv

  conv_k    <<<dim3(5120), dim3(256), 0, stream>>>(x, wq, wk, wv, wo, xb, wqkvT, woT);
  gemm_qkv_k<<<dim3(64,24), dim3(256), 0, stream>>>(xb, wqkvT, qb, kb, vT);
  attn_k    <<<dim3(32,8), dim3(512), 0, stream>>>(qb, kb, vT, ob);
  gemm_out_k<<<dim3(64,8),  dim3(256), 0, stream>>>(ob, woT, out);
}

// Round 14
// 234.489 us; speedup vs baseline: 1.1176x; 1.0189x over previous
//
#include <hip/hip_runtime.h>
#include <hip/hip_bf16.h>
#include <math.h>

typedef unsigned short u16;
typedef unsigned int u32;
typedef __attribute__((ext_vector_type(8))) short bf16x8;   // 8 bf16 = 4 VGPRs
typedef __attribute__((ext_vector_type(4))) float f32x4;
typedef __attribute__((ext_vector_type(16))) float f32x16;

#define MFMA16(a,b,c) __builtin_amdgcn_mfma_f32_16x16x32_bf16(a,b,c,0,0,0)
#define MFMA32(a,b,c) __builtin_amdgcn_mfma_f32_32x32x16_bf16(a,b,c,0,0,0)

__device__ __forceinline__ u16 f2b(float f){
  unsigned u = __float_as_uint(f);
  u += 0x7fffu + ((u >> 16) & 1u);      // RNE
  return (u16)(u >> 16);
}
__device__ __forceinline__ u32 pack2(float a, float b){
  return (u32)f2b(a) | ((u32)f2b(b) << 16);
}
// packed f32x2 -> bf16x2 (RNE), single VALU op
__device__ __forceinline__ u32 cvtpk(float lo, float hi){
  u32 r; asm("v_cvt_pk_bf16_f32 %0, %1, %2" : "=v"(r) : "v"(lo), "v"(hi)); return r;
}

// async global->LDS, 16B per lane; LDS dest = wave-uniform base + lane*16
__device__ __forceinline__ void gll16(const void* g, void* l){
  __builtin_amdgcn_global_load_lds(
      (__attribute__((address_space(1))) void*)(const_cast<void*>(g)),
      (__attribute__((address_space(3))) void*)l, 16, 0, 0);
}

// ---------------- merged conversions ----------------
// blocks [0,4096): x -> bf16.  blocks [4096,5120): transpose-convert weights.
__global__ __launch_bounds__(256) void conv_k(
    const float* __restrict__ x,  const float* __restrict__ wq,
    const float* __restrict__ wk, const float* __restrict__ wv,
    const float* __restrict__ wo, u16* __restrict__ xb,
    u16* __restrict__ wqkvT, u16* __restrict__ woT)
{
  const int bid = blockIdx.x;
  if (bid < 4096){
    size_t i = ((size_t)bid*256 + threadIdx.x)*8;
    float4 a = *(const float4*)(x+i);
    float4 b = *(const float4*)(x+i+4);
    uint4 u;
    u.x = pack2(a.x, a.y);
    u.y = pack2(a.z, a.w);
    u.z = pack2(b.x, b.y);
    u.w = pack2(b.z, b.w);
    *(uint4*)(xb+i) = u;
    return;
  }
  const int id = bid - 4096;            // 0..1023
  const int z = id >> 8, rem = id & 255, i = rem >> 4, j = rem & 15;
  const float* src = (z==0)?wq:(z==1)?wk:(z==2)?wv:wo;
  u16* dst = (z<3) ? (wqkvT + (size_t)z*1024*1024) : woT;
  __shared__ u16 tile[64][72];
  const int t = threadIdx.x;
  const int cr = t >> 4, cc4 = (t & 15) * 4;
#pragma unroll
  for (int rr = 0; rr < 4; rr++){
    int r = rr*16 + cr;
    float4 v = *(const float4*)(src + (size_t)(i*64 + r)*1024 + j*64 + cc4);
    tile[cc4+0][r] = f2b(v.x);
    tile[cc4+1][r] = f2b(v.y);
    tile[cc4+2][r] = f2b(v.z);
    tile[cc4+3][r] = f2b(v.w);
  }
  __syncthreads();
  const int ro = t >> 2, co = (t & 3) * 16;
  uint4 a = *(uint4*)&tile[ro][co];
  uint4 b = *(uint4*)&tile[ro][co+8];
  u16* p = dst + (size_t)(j*64 + ro)*1024 + i*64 + co;
  *(uint4*)p = a;
  *(uint4*)(p+8) = b;
}

// ---------------- 128x128 bf16 GEMM mainloop, BK=64, C = A[M][K] * B[N][K]^T ------
// LDS row = 64 u16 (8 chunks of 8); chunk slot = ch ^ (row&7). 16 iters at K=1024.
// r10 lesson: 256-row tile (8-wave barriers, 2 blocks/CU) was SLOWER than this
// 4-wave structure with 6-deep backfill -- wider barriers lose.
__device__ __forceinline__ void gemm128_bt(
    const u16* __restrict__ A, const u16* __restrict__ B, int K,
    int rowBase, int colBase, f32x4 acc[4][4])
{
  __shared__ __align__(16) u16 lA[128*64];
  __shared__ __align__(16) u16 lB[128*64];
  const int tid = threadIdx.x, lane = tid & 63, wave = tid >> 6;
  const int wr = wave >> 1, wc = wave & 1;
  const int qd = lane >> 4, c = lane & 15;

  int aOff[4], bOff[4];                 // kb=1 offset = kb0 ^ 32
#pragma unroll
  for (int mi=0;mi<4;mi++){ int row = wr*64 + mi*16 + c; aOff[mi] = row*64 + ((qd ^ (row&7))*8); }
#pragma unroll
  for (int ni=0;ni<4;ni++){ int row = wc*64 + ni*16 + c; bOff[ni] = row*64 + ((qd ^ (row&7))*8); }

  const u16* gA[4]; const u16* gB[4]; int seg[4];
#pragma unroll
  for (int cc=0;cc<4;cc++){
    int s = wave*4 + cc;
    int row = s*8 + (lane>>3);
    int gch = (lane&7) ^ (row&7);
    gA[cc] = A + (size_t)(rowBase+row)*K + gch*8;
    gB[cc] = B + (size_t)(colBase+row)*K + gch*8;
    seg[cc] = s*512;
  }
#pragma unroll
  for (int mi=0;mi<4;mi++)
#pragma unroll
    for (int ni=0;ni<4;ni++)
#pragma unroll
      for (int e=0;e<4;e++) acc[mi][ni][e]=0.f;

  for (int k0=0; k0<K; k0+=64){
#pragma unroll
    for (int cc=0;cc<4;cc++){
      gll16(gA[cc] + k0, &lA[seg[cc]]);
      gll16(gB[cc] + k0, &lB[seg[cc]]);
    }
    __syncthreads();
#pragma unroll
    for (int kb=0; kb<2; kb++){
      const int x = kb*32;
      bf16x8 af[4], bb[4];
#pragma unroll
      for (int mi=0;mi<4;mi++) af[mi] = *(const bf16x8*)(lA + (aOff[mi]^x));
#pragma unroll
      for (int ni=0;ni<4;ni++) bb[ni] = *(const bf16x8*)(lB + (bOff[ni]^x));
#pragma unroll
      for (int ni=0;ni<4;ni++)
#pragma unroll
        for (int mi=0;mi<4;mi++)
          acc[mi][ni] = MFMA16(af[mi], bb[ni], acc[mi][ni]);
    }
    __syncthreads();
  }
}

// ---------------- QKV GEMM + RoPE epilogue ----------------
// q pre-scaled by QSC = log2(e)/128 so attention uses exp2 directly.
// RoPE'd dims stored INTERLEAVED: d' = 2j   -> rotated-even of pair j,
//                                 d' = 2j+1 -> rotated-odd  of pair j  (j in [0,32)).
// d' in [64,128) = pass-through. Same permutation for q and k => dot products exact.
// V stored as [bh][t/8][d][8]  ("v8" layout, r12): PV B-operand becomes ONE
// ds_read_b128 at lane-linear addresses (16B stride, conflict-free, no swizzle
// math). qd 0/1 lanes write complementary 8B halves of each 16B cell -> dense.
#define QSC (1.44269504088896f/128.0f)
__global__ __launch_bounds__(256) void gemm_qkv_k(
    const u16* __restrict__ xb, const u16* __restrict__ wqkvT,
    u16* __restrict__ q, u16* __restrict__ k, u16* __restrict__ vT)
{
  f32x4 acc[4][4];
  const int rowBase = blockIdx.x*128, colBase = blockIdx.y*128;
  gemm128_bt(xb, wqkvT, 1024, rowBase, colBase, acc);
  const int tid = threadIdx.x, lane = tid & 63, wave = tid >> 6;
  const int wr = wave >> 1, wc = wave & 1;
  const int qd = lane >> 4, c = lane & 15;
  const int nb = blockIdx.y;
  const int proj = nb >> 3, h = nb & 7;

  if (proj < 2){
    u16* dst = (proj==0) ? q : k;
    const float os = (proj==0) ? QSC : 1.0f;
    if (wc == 0){
      // pairs j=c (tiles 0,2) and j=c+16 (tiles 1,3)
      float ang0 = __powf(10000.0f, -(float)c      * (1.0f/32.0f));
      float ang1 = __powf(10000.0f, -(float)(c+16) * (1.0f/32.0f));
#pragma unroll
      for (int mi=0;mi<4;mi++){
#pragma unroll
        for (int r=0;r<4;r++){
          int row = rowBase + wr*64 + mi*16 + qd*4 + r;
          int b = row >> 11, t = row & 2047;
          u32* dst32 = (u32*)(dst + (((long)(b*8+h))*2048 + t)*128);
          float s0,c0,s1,c1;
          __sincosf((float)t*ang0, &s0, &c0);
          __sincosf((float)t*ang1, &s1, &c1);
          { float e = acc[mi][0][r], od = acc[mi][2][r];
            dst32[c]      = pack2((e*c0 - od*s0)*os, (e*s0 + od*c0)*os); }
          { float e = acc[mi][1][r], od = acc[mi][3][r];
            dst32[16 + c] = pack2((e*c1 - od*s1)*os, (e*s1 + od*c1)*os); }
        }
      }
    } else {
      // pass-through half d in [64,128)
#pragma unroll
      for (int mi=0;mi<4;mi++){
#pragma unroll
        for (int r=0;r<4;r++){
          int row = rowBase + wr*64 + mi*16 + qd*4 + r;
          int b = row >> 11, t = row & 2047;
          long base = (((long)(b*8+h))*2048 + t)*128 + 64;
#pragma unroll
          for (int ni=0;ni<4;ni++)
            dst[base + ni*16 + c] = f2b(acc[mi][ni][r]*os);
        }
      }
    }
  } else {
    // v: [bh][t/8][d][8]; acc[mi][ni][0..3] = 4 consecutive t at one d.
#pragma unroll
    for (int mi=0;mi<4;mi++){
      int row0 = rowBase + wr*64 + mi*16 + qd*4;
      int b = row0 >> 11, t = row0 & 2047;
      long base = ((long)(b*8+h)*256 + (t>>3)) * 1024 + (t&7);
#pragma unroll
      for (int ni=0;ni<4;ni++){
        int d = wc*64 + ni*16 + c;
        *(uint2*)(vT + base + d*8) = make_uint2(pack2(acc[mi][ni][0], acc[mi][ni][1]),
                                                pack2(acc[mi][ni][2], acc[mi][ni][3]));
      }
    }
  }
}

// ---------------- flash attention (r11 + v8 V reads) ----------------
// 256 blocks x 512 thr, heavy+light sub pairing, KVBLK=64, 1 block/CU.
// T12: P fully in-register via cvt_pk_bf16 + permlane32_swap (HW-verified r3).
// r11: QK split into two independent 4-MFMA chains (interleaved issue).
// r12: V in v8 layout -> PV B-operand is ONE ds_read_b128 per MFMA (was 2x b64),
// lane-linear addresses, no swizzle VALU. Body is VALU-issue-bound (r11: 47.7%).
// K in LDS [2][64 key][128 d] swiz ^(row&15); V in LDS [2][8 t8][128 d][8] linear.
__global__ __launch_bounds__(512, 2) void attn_k(
    const u16* __restrict__ q, const u16* __restrict__ k,
    const u16* __restrict__ vT, u16* __restrict__ o)
{
  __shared__ __align__(16) u16 smem[33280];        // 65 KB
  u16* lK = smem;                                  // [2][64 key][128 d], swiz ^(row&15)
  u16* lV = smem + 16384;                          // [2][8 t8][128 d][8], linear
  float* scrO = (float*)smem;                      // epilogue [16][32][32] f32 = 64KB
  float* scrL = (float*)(smem + 32768);            // epilogue [2][128] (bytes 64K..65K)

  const int tid = threadIdx.x, lane = tid & 63, wave = tid >> 6;
  const int h2 = lane >> 5, ln = lane & 31;
  const int qs = wave >> 1, kh = wave & 1;
  const int bh = blockIdx.x, p = blockIdx.y;

  auto loadKV = [&](int kt, int buf){
    const u16* kSrc = k + ((long)bh*2048 + kt*64)*128;
#pragma unroll
    for (int cc=0; cc<2; cc++){
      int s = wave*2+cc;
      int row = s*4 + (lane>>4);
      int gch = (lane&15) ^ (row&15);
      gll16(kSrc + row*128 + gch*8, lK + buf*8192 + s*512);
    }
    const u16* vSrc = vT + (long)bh*262144 + (long)kt*8192;   // 16KB tile, contiguous
#pragma unroll
    for (int cc=0; cc<2; cc++){
      int s = wave*2+cc;
      gll16(vSrc + s*512 + lane*8, lV + buf*8192 + s*512);
    }
  };

  for (int sub=0; sub<2; sub++){
    const int qt = sub ? (15 - p) : p;
    const int q0 = qt*128;
    const int qw = q0 + qs*32;          // wave's q-strip base

    bf16x8 aQ[8];
    {
      const long qrow = (long)bh*2048 + qw + ln;
#pragma unroll
      for (int ch=0; ch<8; ch++)
        aQ[ch] = *(const bf16x8*)(q + qrow*128 + ch*16 + h2*8);
    }
    f32x16 accO[4];
#pragma unroll
    for (int dt=0; dt<4; dt++)
#pragma unroll
      for (int r=0;r<16;r++) accO[dt][r] = 0.f;
    float lsum = 0.f;

    __syncthreads();                    // prior sub's LDS users done
    loadKV(0, 0);
    int cur = 0;
    const int ktMax = 2*qt + 1;

    for (int kt=0; kt<=ktMax; kt++){
      __syncthreads();                  // buf[cur] ready; buf[cur^1] readers done
      if (kt < ktMax) loadKV(kt+1, cur^1);

      const int key0 = kt*64 + kh*32;
      if (key0 <= qw + 31){             // not fully masked for this wave
        // S^T[key][q] 32x32: A = K-half, B = Q-strip.
        // Two independent accumulation chains, interleaved issue (r11).
        f32x16 s0v, s1v;
#pragma unroll
        for (int r=0;r<16;r++){ s0v[r]=0.f; s1v[r]=0.f; }
        const int krow = kh*32 + ln;
#pragma unroll
        for (int ch=0; ch<4; ch++){
          bf16x8 ak0 = *(const bf16x8*)(lK + cur*8192 + krow*128 + ((((ch  )*2+h2) ^ (krow&15))*8));
          bf16x8 ak1 = *(const bf16x8*)(lK + cur*8192 + krow*128 + ((((ch+4)*2+h2) ^ (krow&15))*8));
          s0v = MFMA32(ak0, aQ[ch],   s0v);
          s1v = MFMA32(ak1, aQ[ch+4], s1v);
        }

        const bool diag = (key0 + 31 > qw);
        float pe[16];
        float ls0 = 0.f, ls1 = 0.f;
#pragma unroll
        for (int r=0;r<16;r++){
          float s = s0v[r] + s1v[r];
          if (diag){
            int keyg = key0 + (r&3) + 8*(r>>2) + 4*h2;
            if (keyg > qw + ln) s = -INFINITY;   // exp2(-inf) = 0
          }
          pe[r] = exp2f(s);
          if (r & 1) ls1 += pe[r]; else ls0 += pe[r];
        }
        lsum += ls0 + ls1;

        // ---- P -> MFMA A-fragments fully in-register (T12, verified r3) ----
        u32 w0 = cvtpk(pe[0],  pe[1]),  w1 = cvtpk(pe[2],  pe[3]);
        u32 w2 = cvtpk(pe[4],  pe[5]),  w3 = cvtpk(pe[6],  pe[7]);
        u32 w4 = cvtpk(pe[8],  pe[9]),  w5 = cvtpk(pe[10], pe[11]);
        u32 w6 = cvtpk(pe[12], pe[13]), w7 = cvtpk(pe[14], pe[15]);
        asm volatile("v_permlane32_swap_b32 %0, %1" : "+v"(w0), "+v"(w2));
        asm volatile("v_permlane32_swap_b32 %0, %1" : "+v"(w1), "+v"(w3));
        asm volatile("v_permlane32_swap_b32 %0, %1" : "+v"(w4), "+v"(w6));
        asm volatile("v_permlane32_swap_b32 %0, %1" : "+v"(w5), "+v"(w7));
        union { bf16x8 v; u32 u[4]; } ap0, ap1;
        ap0.u[0]=w0; ap0.u[1]=w1; ap0.u[2]=w2; ap0.u[3]=w3;   // keys key0+ 0..15
        ap1.u[0]=w4; ap1.u[1]=w5; ap1.u[2]=w6; ap1.u[3]=w7;   // keys key0+16..31

        // O[q][d] partial: A = P fragment, B = V (v8 layout: single b128 read)
#pragma unroll
        for (int kk=0; kk<2; kk++){
          bf16x8 ap = kk ? ap1.v : ap0.v;
          const int t8 = kh*4 + kk*2 + h2;      // 8-key group within 64-key tile
#pragma unroll
          for (int dt=0; dt<4; dt++){
            int d = dt*32 + ln;
            bf16x8 bv = *(const bf16x8*)(lV + cur*8192 + (t8*128 + d)*8);
            accO[dt] = MFMA32(ap, bv, accO[dt]);
          }
        }
      }
      cur ^= 1;
    }

    // ---- epilogue: combine kh halves, normalize, store ----
    lsum += __shfl_xor(lsum, 32);       // fold h2 halves
    __syncthreads();                    // main-loop LDS reads done before alias reuse
    if (kh == 1){
#pragma unroll
      for (int dt=0; dt<4; dt++)
#pragma unroll
      for (int r=0;r<16;r++){
        int row = (r&3) + 8*(r>>2) + 4*h2;
        scrO[((qs*4+dt)*32 + row)*32 + ln] = accO[dt][r];
      }
      if (h2 == 0) scrL[128 + qs*32 + ln] = lsum;
    } else {
      if (h2 == 0) scrL[qs*32 + ln] = lsum;
    }
    __syncthreads();
    if (kh == 0){
      float linv[16];
#pragma unroll
      for (int r=0;r<16;r++){
        int row = (r&3) + 8*(r>>2) + 4*h2;
        linv[r] = 1.0f / (scrL[qs*32 + row] + scrL[128 + qs*32 + row]);
      }
      const int b = bh >> 3, h = bh & 7;
#pragma unroll
      for (int dt=0; dt<4; dt++){
#pragma unroll
        for (int r=0;r<16;r++){
          int row = (r&3) + 8*(r>>2) + 4*h2;
          float val = accO[dt][r] + scrO[((qs*4+dt)*32 + row)*32 + ln];
          int t = q0 + qs*32 + row;
          o[((long)(b*2048 + t))*1024 + h*128 + dt*32 + ln] = f2b(val * linv[r]);
        }
      }
    }
  }
}

// ---------------- output projection ----------------
__global__ __launch_bounds__(256) void gemm_out_k(
    const u16* __restrict__ oa, const u16* __restrict__ woT, float* __restrict__ out)
{
  f32x4 acc[4][4];
  const int rowBase = blockIdx.x*128, colBase = blockIdx.y*128;
  gemm128_bt(oa, woT, 1024, rowBase, colBase, acc);
  const int lane = threadIdx.x & 63, wave = threadIdx.x >> 6;
  const int wr = wave >> 1, wc = wave & 1;
  const int qd = lane >> 4, c = lane & 15;
#pragma unroll
  for (int mi=0;mi<4;mi++){
#pragma unroll
    for (int ni=0;ni<4;ni++){
      int row = rowBase + wr*64 + mi*16 + qd*4;
      int col = colBase + wc*64 + ni*16 + c;
#pragma unroll
      for (int r=0;r<4;r++)
        out[(size_t)(row+r)*1024 + col] = acc[mi][ni][r];
    }
  }
}

extern "C" void kernel_launch(void* const* d_in, const int* in_sizes, int n_in,
                              void* d_out, int out_size, void* d_ws, size_t ws_size,
                              hipStream_t stream) {
  const float* x  = (const float*)d_in[0];
  const float* wq = (const float*)d_in[1];
  const float* wk = (const float*)d_in[2];
  const float* wv = (const float*)d_in[3];
  const float* wo = (const float*)d_in[4];
  float* out = (float*)d_out;

  char* ws = (char*)d_ws;
  u16* xb    = (u16*)(ws);
  u16* wqkvT = (u16*)(ws + (16u<<20));
  u16* woT   = (u16*)(ws + (22u<<20));
  u16* qb    = (u16*)(ws + (24u<<20));
  u16* kb    = (u16*)(ws + (40u<<20));
  u16* vT    = (u16*)(ws + (56u<<20));
  u16* ob    = xb;   // reuse xb after gemm_qkv

  conv_k    <<<dim3(5120), dim3(256), 0, stream>>>(x, wq, wk, wv, wo, xb, wqkvT, woT);
  gemm_qkv_k<<<dim3(64,24), dim3(256), 0, stream>>>(xb, wqkvT, qb, kb, vT);
  attn_k    <<<dim3(32,8), dim3(512), 0, stream>>>(qb, kb, vT, ob);
  gemm_out_k<<<dim3(64,8),  dim3(256), 0, stream>>>(ob, woT, out);
}